// Round 1
// baseline (5496.244 us; speedup 1.0000x reference)
//
#include <hip/hip_runtime.h>
#include <hip/hip_bf16.h>

// Problem dims
#define B_    4
#define T_    512
#define H_    768
#define N_    256
#define S_    16
#define NERD  32
#define D_    800      // H + NER_DIM
#define L_    2
#define R_    15
#define NE_   64
#define MM_   8
#define P_    1024
#define E_    4096
#define OUT_  97
#define KR    (R_ * D_)    // 12000
#define KA    (KR + D_)    // 12800 (concat [aggH | h] along K)
#define EE2   1600         // 2*D
#define KF    (4 * EE2)    // 6400
#define NH    (2 * EE2)    // 3200

// ---------------------------------------------------------------- doc_proj
__global__ __launch_bounds__(256) void k_doc_proj(
    const float* __restrict__ doc_cls, const float* __restrict__ doc_W,
    const float* __restrict__ doc_b, float* __restrict__ doc_proj) {
  int i = blockIdx.x * 256 + threadIdx.x;
  if (i >= B_ * D_) return;
  int b = i / D_, d = i % D_;
  float acc = doc_b[d];
  const float* dc = doc_cls + b * H_;
#pragma unroll 4
  for (int k = 0; k < H_; k++) acc += dc[k] * doc_W[k * D_ + d];
  doc_proj[i] = fmaxf(acc, 0.f);
}

// ---------------------------------------------------------------- node build
__global__ __launch_bounds__(256) void k_build_node(
    const float* __restrict__ tokf, const float* __restrict__ doc_cls,
    const int* __restrict__ span_pos, const float* __restrict__ span_mask,
    const int* __restrict__ node_ner, const float* __restrict__ node_mask,
    const int* __restrict__ ment_num, const float* __restrict__ nerEmb,
    const float* __restrict__ doc_proj, float* __restrict__ x) {
  int n = blockIdx.x, b = blockIdx.y;
  __shared__ int pos_s[S_];
  __shared__ float msk_s[S_];
  int tid = threadIdx.x;
  if (tid < S_) {
    pos_s[tid] = span_pos[((size_t)b * N_ + n) * S_ + tid];
    msk_s[tid] = span_mask[((size_t)b * N_ + n) * S_ + tid];
  }
  __syncthreads();
  float msum = 0.f;
#pragma unroll
  for (int s = 0; s < S_; s++) msum += msk_s[s];
  float rinv = 1.f / (msum + 0.1f);
  int m = ment_num[b];
  float nm = node_mask[b * N_ + n];
  int ner = node_ner[b * N_ + n];
  for (int d = tid; d < D_; d += 256) {
    float v;
    if (d < H_) {
      float ssum = 0.f;
#pragma unroll
      for (int s = 0; s < S_; s++)
        ssum += tokf[((size_t)b * T_ + pos_s[s]) * H_ + d] * msk_s[s];
      v = ssum * rinv + doc_cls[b * H_ + d];
    } else {
      v = nerEmb[ner * NERD + (d - H_)];
    }
    v *= nm;
    if (n == m) v = doc_proj[b * D_ + d];  // x.at[m].set(doc_proj)
    x[((size_t)b * N_ + n) * D_ + d] = v;
  }
}

// ---------------------------------------------------------------- per-layer prep: zero aggH, copy h into tail
__global__ __launch_bounds__(256) void k_prep(const float* __restrict__ h,
                                              float* __restrict__ aggA) {
  int n = blockIdx.x, b = blockIdx.y;
  float4* row = (float4*)(aggA + ((size_t)b * N_ + n) * KA);
  const float4* hr = (const float4*)(h + ((size_t)b * N_ + n) * D_);
  float4 z = {0.f, 0.f, 0.f, 0.f};
  int tid = threadIdx.x;
  for (int i = tid; i < KR / 4; i += 256) row[i] = z;          // 3000 float4
  for (int i = tid; i < D_ / 4; i += 256) row[KR / 4 + i] = hr[i];  // 200 float4
}

// ---------------------------------------------------------------- edge scatter: aggA[b,dst, rel*800:] += h[b,src]
__global__ __launch_bounds__(256) void k_scatter(
    const float* __restrict__ h, const int* __restrict__ esrc,
    const int* __restrict__ edst, const int* __restrict__ erel,
    float* __restrict__ aggA) {
  int e = blockIdx.x, b = blockIdx.y;
  size_t ei = (size_t)b * E_ + e;
  int src = esrc[ei], dst = edst[ei], rel = erel[ei];
  const float* hs = h + ((size_t)b * N_ + src) * D_;
  float* dp = aggA + ((size_t)b * N_ + dst) * KA + (size_t)rel * D_;
  for (int d = threadIdx.x; d < D_; d += 256) atomicAdd(dp + d, hs[d]);
}

// ---------------------------------------------------------------- GNN GEMM: hout = relu([aggH|h] @ [W_rel;W_self] + b)
// per-sample M=256, N=800, K=12800. 64x64x16 tile, 4x4/thread.
__global__ __launch_bounds__(256) void k_gnn_gemm(
    const float* __restrict__ aggA, const float* __restrict__ W_rel,
    const float* __restrict__ W_self, const float* __restrict__ gnn_b,
    int layer, float* __restrict__ hout) {
  __shared__ float As[16][68];
  __shared__ float Bs[16][68];
  int b = blockIdx.z;
  int m0 = blockIdx.y * 64;
  int n0 = blockIdx.x * 64;
  int tid = threadIdx.x;
  int am = tid >> 2, ak = (tid & 3) << 2;
  int bk = tid >> 4, bn = (tid & 15) << 2;
  int rm = (tid >> 4) << 2, cn = (tid & 15) << 2;
  const float* Arow = aggA + ((size_t)b * N_ + m0 + am) * KA + ak;
  const float* Wl_rel = W_rel + (size_t)layer * KR * D_;
  const float* Wl_self = W_self + (size_t)layer * D_ * D_;
  float acc[4][4] = {};
  for (int kt = 0; kt < KA; kt += 16) {
    float4 a4 = *(const float4*)(Arow + kt);
    As[ak + 0][am] = a4.x; As[ak + 1][am] = a4.y;
    As[ak + 2][am] = a4.z; As[ak + 3][am] = a4.w;
    int kg = kt + bk;
    const float* Bp = (kg < KR) ? (Wl_rel + (size_t)kg * D_)
                                : (Wl_self + (size_t)(kg - KR) * D_);
    int col = n0 + bn;
    float4 b4;
    if (col + 3 < D_) {
      b4 = *(const float4*)(Bp + col);
    } else {
      b4.x = (col + 0 < D_) ? Bp[col + 0] : 0.f;
      b4.y = (col + 1 < D_) ? Bp[col + 1] : 0.f;
      b4.z = (col + 2 < D_) ? Bp[col + 2] : 0.f;
      b4.w = (col + 3 < D_) ? Bp[col + 3] : 0.f;
    }
    *(float4*)&Bs[bk][bn] = b4;
    __syncthreads();
#pragma unroll
    for (int kk = 0; kk < 16; kk++) {
      float4 a = *(const float4*)&As[kk][rm];
      float4 bb = *(const float4*)&Bs[kk][cn];
      float av[4] = {a.x, a.y, a.z, a.w};
      float bv[4] = {bb.x, bb.y, bb.z, bb.w};
#pragma unroll
      for (int i = 0; i < 4; i++)
#pragma unroll
        for (int j = 0; j < 4; j++) acc[i][j] += av[i] * bv[j];
    }
    __syncthreads();
  }
#pragma unroll
  for (int i = 0; i < 4; i++) {
    int row = m0 + rm + i;
#pragma unroll
    for (int j = 0; j < 4; j++) {
      int col = n0 + cn + j;
      if (col < D_)
        hout[((size_t)b * N_ + row) * D_ + col] =
            fmaxf(acc[i][j] + gnn_b[layer * D_ + col], 0.f);
    }
  }
}

// ---------------------------------------------------------------- entity mention-mean
__global__ __launch_bounds__(256) void k_ent(
    const float* __restrict__ h0, const float* __restrict__ h1,
    const int* __restrict__ e2m, const float* __restrict__ e2m_mask,
    float* __restrict__ ent) {
  int e = blockIdx.x, b = blockIdx.y;
  __shared__ int idx_s[MM_];
  __shared__ float msk_s[MM_];
  int tid = threadIdx.x;
  if (tid < MM_) {
    idx_s[tid] = e2m[((size_t)b * NE_ + e) * MM_ + tid];
    msk_s[tid] = e2m_mask[((size_t)b * NE_ + e) * MM_ + tid];
  }
  __syncthreads();
  float msum = 0.f;
#pragma unroll
  for (int m = 0; m < MM_; m++) msum += msk_s[m];
  float inv = 1.f / (msum + 1e-7f);
  for (int c = tid; c < EE2; c += 256) {
    const float* base = (c < D_) ? h0 : h1;
    int cc = (c < D_) ? c : c - D_;
    float s = 0.f;
#pragma unroll
    for (int m = 0; m < MM_; m++) {
      int j = idx_s[m];
      if (j > 0) s += base[((size_t)b * N_ + (j - 1)) * D_ + cc] * msk_s[m];
    }
    ent[((size_t)b * NE_ + e) * EE2 + c] = s * inv;
  }
}

// ---------------------------------------------------------------- MLP layer1: hidden = relu(feat @ W1 + b1)
// M=4096 (b,p), N=3200, K=6400; feat synthesized on the fly from ent + pairs.
__global__ __launch_bounds__(256) void k_mlp1(
    const float* __restrict__ ent, const int* __restrict__ ent_pair,
    const float* __restrict__ W1, const float* __restrict__ b1,
    float* __restrict__ hidden) {
  __shared__ float As[16][68];
  __shared__ float Bs[16][68];
  __shared__ int ph[64], pt[64];
  int n0 = blockIdx.x * 64;
  int row0 = blockIdx.y * 64;
  int b = row0 >> 10;  // 1024 rows per sample; 64 | 1024 so tile is within one b
  int tid = threadIdx.x;
  if (tid < 64) {
    int g = (row0 & 1023) + tid;
    ph[tid] = ent_pair[(((size_t)b << 10) + g) * 2 + 0];
    pt[tid] = ent_pair[(((size_t)b << 10) + g) * 2 + 1];
  }
  __syncthreads();
  int am = tid >> 2, ak = (tid & 3) << 2;
  int bk = tid >> 4, bn = (tid & 15) << 2;
  int rm = (tid >> 4) << 2, cn = (tid & 15) << 2;
  const float* entb = ent + (size_t)b * NE_ * EE2;
  const float* eh = entb + (size_t)ph[am] * EE2;
  const float* et = entb + (size_t)pt[am] * EE2;
  float acc[4][4] = {};
  for (int kt = 0; kt < KF; kt += 16) {
    int k = kt + ak;
    int seg = k / EE2, kk = k % EE2;  // 16 | 1600, so no straddle within float4
    float4 hf = *(const float4*)(eh + kk);
    float4 tf = *(const float4*)(et + kk);
    float4 v;
    if (seg == 0) v = hf;
    else if (seg == 1) v = tf;
    else if (seg == 2) {
      v.x = fabsf(hf.x - tf.x); v.y = fabsf(hf.y - tf.y);
      v.z = fabsf(hf.z - tf.z); v.w = fabsf(hf.w - tf.w);
    } else {
      v.x = hf.x * tf.x; v.y = hf.y * tf.y;
      v.z = hf.z * tf.z; v.w = hf.w * tf.w;
    }
    As[ak + 0][am] = v.x; As[ak + 1][am] = v.y;
    As[ak + 2][am] = v.z; As[ak + 3][am] = v.w;
    float4 b4 = *(const float4*)(W1 + (size_t)(kt + bk) * NH + n0 + bn);
    *(float4*)&Bs[bk][bn] = b4;
    __syncthreads();
#pragma unroll
    for (int kkk = 0; kkk < 16; kkk++) {
      float4 a = *(const float4*)&As[kkk][rm];
      float4 bb = *(const float4*)&Bs[kkk][cn];
      float av[4] = {a.x, a.y, a.z, a.w};
      float bv[4] = {bb.x, bb.y, bb.z, bb.w};
#pragma unroll
      for (int i = 0; i < 4; i++)
#pragma unroll
        for (int j = 0; j < 4; j++) acc[i][j] += av[i] * bv[j];
    }
    __syncthreads();
  }
#pragma unroll
  for (int i = 0; i < 4; i++) {
    int row = row0 + rm + i;
#pragma unroll
    for (int j = 0; j < 4; j++) {
      int col = n0 + cn + j;
      hidden[(size_t)row * NH + col] = fmaxf(acc[i][j] + b1[col], 0.f);
    }
  }
}

// ---------------------------------------------------------------- MLP layer2: out = hidden @ W2 + b2
__global__ __launch_bounds__(128) void k_mlp2(
    const float* __restrict__ hidden, const float* __restrict__ W2,
    const float* __restrict__ b2, float* __restrict__ out) {
  __shared__ float hrow[NH];
  int row = blockIdx.x;
  const float* hr = hidden + (size_t)row * NH;
  for (int i = threadIdx.x; i < NH; i += 128) hrow[i] = hr[i];
  __syncthreads();
  int t = threadIdx.x;
  if (t < OUT_) {
    float acc = b2[t];
#pragma unroll 8
    for (int k = 0; k < NH; k++) acc += hrow[k] * W2[k * OUT_ + t];
    out[(size_t)row * OUT_ + t] = acc;
  }
}

// ----------------------------------------------------------------
extern "C" void kernel_launch(void* const* d_in, const int* in_sizes, int n_in,
                              void* d_out, int out_size, void* d_ws, size_t ws_size,
                              hipStream_t stream) {
  const float* token_feature = (const float*)d_in[0];
  const float* doc_cls       = (const float*)d_in[1];
  const int*   span_pos      = (const int*)d_in[2];
  const float* span_mask     = (const float*)d_in[3];
  const int*   node_ner      = (const int*)d_in[4];
  const float* node_mask     = (const float*)d_in[5];
  const int*   e2m           = (const int*)d_in[6];
  const float* e2m_mask      = (const float*)d_in[7];
  const int*   ent_pair      = (const int*)d_in[8];
  const int*   edge_src      = (const int*)d_in[9];
  const int*   edge_dst      = (const int*)d_in[10];
  const int*   edge_rel      = (const int*)d_in[11];
  const int*   ment_num      = (const int*)d_in[12];
  const float* nerEmb        = (const float*)d_in[13];
  const float* doc_W         = (const float*)d_in[14];
  const float* doc_b         = (const float*)d_in[15];
  const float* W_rel         = (const float*)d_in[16];
  const float* W_self        = (const float*)d_in[17];
  const float* gnn_b         = (const float*)d_in[18];
  const float* W1            = (const float*)d_in[19];
  const float* b1            = (const float*)d_in[20];
  const float* W2            = (const float*)d_in[21];
  const float* b2            = (const float*)d_in[22];
  float* out = (float*)d_out;

  float* ws = (float*)d_ws;
  size_t off = 0;
  auto alloc = [&](size_t n) {
    float* p = ws + off;
    off += (n + 63) & ~size_t(63);
    return p;
  };
  float* doc_proj = alloc(B_ * D_);
  float* x    = alloc((size_t)B_ * N_ * D_);
  float* h0   = alloc((size_t)B_ * N_ * D_);
  float* h1   = alloc((size_t)B_ * N_ * D_);
  float* aggA = alloc((size_t)B_ * N_ * KA);
  float* ent  = alloc((size_t)B_ * NE_ * EE2);
  float* hidden = alloc((size_t)B_ * P_ * NH);
  (void)ws_size;

  k_doc_proj<<<dim3((B_ * D_ + 255) / 256), 256, 0, stream>>>(doc_cls, doc_W, doc_b, doc_proj);
  k_build_node<<<dim3(N_, B_), 256, 0, stream>>>(token_feature, doc_cls, span_pos, span_mask,
                                                 node_ner, node_mask, ment_num, nerEmb,
                                                 doc_proj, x);
  const float* hin = x;
  float* houts[2] = {h0, h1};
  for (int l = 0; l < L_; l++) {
    k_prep<<<dim3(N_, B_), 256, 0, stream>>>(hin, aggA);
    k_scatter<<<dim3(E_, B_), 256, 0, stream>>>(hin, edge_src, edge_dst, edge_rel, aggA);
    k_gnn_gemm<<<dim3(13, 4, B_), 256, 0, stream>>>(aggA, W_rel, W_self, gnn_b, l, houts[l]);
    hin = houts[l];
  }
  k_ent<<<dim3(NE_, B_), 256, 0, stream>>>(h0, h1, e2m, e2m_mask, ent);
  k_mlp1<<<dim3(NH / 64, (B_ * P_) / 64), 256, 0, stream>>>(ent, ent_pair, W1, b1, hidden);
  k_mlp2<<<dim3(B_ * P_), 128, 0, stream>>>(hidden, W2, b2, out);
}

// Round 2
// 3231.525 us; speedup vs baseline: 1.7008x; 1.7008x over previous
//
#include <hip/hip_runtime.h>
#include <hip/hip_bf16.h>

// Problem dims
#define B_    4
#define T_    512
#define H_    768
#define N_    256
#define S_    16
#define NERD  32
#define D_    800      // H + NER_DIM
#define L_    2
#define R_    15
#define NE_   64
#define MM_   8
#define P_    1024
#define E_    4096
#define OUT_  97
#define KR    (R_ * D_)    // 12000
#define KA    (KR + D_)    // 12800 (concat [aggH | h] along K)
#define EE2   1600         // 2*D
#define KF    (4 * EE2)    // 6400
#define NH    (2 * EE2)    // 3200

typedef unsigned short u16;
typedef unsigned int   u32;
typedef __attribute__((ext_vector_type(8))) short  short8;
typedef __attribute__((ext_vector_type(4))) float  f32x4;

#define AS1 __attribute__((address_space(1)))
#define AS3 __attribute__((address_space(3)))

static __device__ __forceinline__ u16 f2bf(float f) {
  union { float f; u32 u; } v; v.f = f;
  u32 u = v.u;
  u32 r = (u + 0x7FFFu + ((u >> 16) & 1u)) >> 16;  // round-nearest-even
  return (u16)r;
}

// ---------------------------------------------------------------- doc_proj
__global__ __launch_bounds__(256) void k_doc_proj(
    const float* __restrict__ doc_cls, const float* __restrict__ doc_W,
    const float* __restrict__ doc_b, float* __restrict__ doc_proj) {
  int i = blockIdx.x * 256 + threadIdx.x;
  if (i >= B_ * D_) return;
  int b = i / D_, d = i % D_;
  float acc = doc_b[d];
  const float* dc = doc_cls + b * H_;
#pragma unroll 4
  for (int k = 0; k < H_; k++) acc += dc[k] * doc_W[k * D_ + d];
  doc_proj[i] = fmaxf(acc, 0.f);
}

// ---------------------------------------------------------------- node build
__global__ __launch_bounds__(256) void k_build_node(
    const float* __restrict__ tokf, const float* __restrict__ doc_cls,
    const int* __restrict__ span_pos, const float* __restrict__ span_mask,
    const int* __restrict__ node_ner, const float* __restrict__ node_mask,
    const int* __restrict__ ment_num, const float* __restrict__ nerEmb,
    const float* __restrict__ doc_proj, float* __restrict__ x) {
  int n = blockIdx.x, b = blockIdx.y;
  __shared__ int pos_s[S_];
  __shared__ float msk_s[S_];
  int tid = threadIdx.x;
  if (tid < S_) {
    pos_s[tid] = span_pos[((size_t)b * N_ + n) * S_ + tid];
    msk_s[tid] = span_mask[((size_t)b * N_ + n) * S_ + tid];
  }
  __syncthreads();
  float msum = 0.f;
#pragma unroll
  for (int s = 0; s < S_; s++) msum += msk_s[s];
  float rinv = 1.f / (msum + 0.1f);
  int m = ment_num[b];
  float nm = node_mask[b * N_ + n];
  int ner = node_ner[b * N_ + n];
  for (int d = tid; d < D_; d += 256) {
    float v;
    if (d < H_) {
      float ssum = 0.f;
#pragma unroll
      for (int s = 0; s < S_; s++)
        ssum += tokf[((size_t)b * T_ + pos_s[s]) * H_ + d] * msk_s[s];
      v = ssum * rinv + doc_cls[b * H_ + d];
    } else {
      v = nerEmb[ner * NERD + (d - H_)];
    }
    v *= nm;
    if (n == m) v = doc_proj[b * D_ + d];  // x.at[m].set(doc_proj)
    x[((size_t)b * N_ + n) * D_ + d] = v;
  }
}

// ---------------------------------------------------------------- per-layer prep: zero aggH, copy h into tail
__global__ __launch_bounds__(256) void k_prep(const float* __restrict__ h,
                                              float* __restrict__ aggA) {
  int n = blockIdx.x, b = blockIdx.y;
  float4* row = (float4*)(aggA + ((size_t)b * N_ + n) * KA);
  const float4* hr = (const float4*)(h + ((size_t)b * N_ + n) * D_);
  float4 z = {0.f, 0.f, 0.f, 0.f};
  int tid = threadIdx.x;
  for (int i = tid; i < KR / 4; i += 256) row[i] = z;
  for (int i = tid; i < D_ / 4; i += 256) row[KR / 4 + i] = hr[i];
}

// ---------------------------------------------------------------- edge scatter
__global__ __launch_bounds__(256) void k_scatter(
    const float* __restrict__ h, const int* __restrict__ esrc,
    const int* __restrict__ edst, const int* __restrict__ erel,
    float* __restrict__ aggA) {
  int e = blockIdx.x, b = blockIdx.y;
  size_t ei = (size_t)b * E_ + e;
  int src = esrc[ei], dst = edst[ei], rel = erel[ei];
  const float* hs = h + ((size_t)b * N_ + src) * D_;
  float* dp = aggA + ((size_t)b * N_ + dst) * KA + (size_t)rel * D_;
  for (int d = threadIdx.x; d < D_; d += 256) atomicAdd(dp + d, hs[d]);
}

// ---------------------------------------------------------------- GNN GEMM (fp32)
__global__ __launch_bounds__(256) void k_gnn_gemm(
    const float* __restrict__ aggA, const float* __restrict__ W_rel,
    const float* __restrict__ W_self, const float* __restrict__ gnn_b,
    int layer, float* __restrict__ hout) {
  __shared__ float As[16][68];
  __shared__ float Bs[16][68];
  int b = blockIdx.z;
  int m0 = blockIdx.y * 64;
  int n0 = blockIdx.x * 64;
  int tid = threadIdx.x;
  int am = tid >> 2, ak = (tid & 3) << 2;
  int bk = tid >> 4, bn = (tid & 15) << 2;
  int rm = (tid >> 4) << 2, cn = (tid & 15) << 2;
  const float* Arow = aggA + ((size_t)b * N_ + m0 + am) * KA + ak;
  const float* Wl_rel = W_rel + (size_t)layer * KR * D_;
  const float* Wl_self = W_self + (size_t)layer * D_ * D_;
  float acc[4][4] = {};
  for (int kt = 0; kt < KA; kt += 16) {
    float4 a4 = *(const float4*)(Arow + kt);
    As[ak + 0][am] = a4.x; As[ak + 1][am] = a4.y;
    As[ak + 2][am] = a4.z; As[ak + 3][am] = a4.w;
    int kg = kt + bk;
    const float* Bp = (kg < KR) ? (Wl_rel + (size_t)kg * D_)
                                : (Wl_self + (size_t)(kg - KR) * D_);
    int col = n0 + bn;
    float4 b4;
    if (col + 3 < D_) {
      b4 = *(const float4*)(Bp + col);
    } else {
      b4.x = (col + 0 < D_) ? Bp[col + 0] : 0.f;
      b4.y = (col + 1 < D_) ? Bp[col + 1] : 0.f;
      b4.z = (col + 2 < D_) ? Bp[col + 2] : 0.f;
      b4.w = (col + 3 < D_) ? Bp[col + 3] : 0.f;
    }
    *(float4*)&Bs[bk][bn] = b4;
    __syncthreads();
#pragma unroll
    for (int kk = 0; kk < 16; kk++) {
      float4 a = *(const float4*)&As[kk][rm];
      float4 bb = *(const float4*)&Bs[kk][cn];
      float av[4] = {a.x, a.y, a.z, a.w};
      float bv[4] = {bb.x, bb.y, bb.z, bb.w};
#pragma unroll
      for (int i = 0; i < 4; i++)
#pragma unroll
        for (int j = 0; j < 4; j++) acc[i][j] += av[i] * bv[j];
    }
    __syncthreads();
  }
#pragma unroll
  for (int i = 0; i < 4; i++) {
    int row = m0 + rm + i;
#pragma unroll
    for (int j = 0; j < 4; j++) {
      int col = n0 + cn + j;
      if (col < D_)
        hout[((size_t)b * N_ + row) * D_ + col] =
            fmaxf(acc[i][j] + gnn_b[layer * D_ + col], 0.f);
    }
  }
}

// ---------------------------------------------------------------- entity mention-mean
__global__ __launch_bounds__(256) void k_ent(
    const float* __restrict__ h0, const float* __restrict__ h1,
    const int* __restrict__ e2m, const float* __restrict__ e2m_mask,
    float* __restrict__ ent) {
  int e = blockIdx.x, b = blockIdx.y;
  __shared__ int idx_s[MM_];
  __shared__ float msk_s[MM_];
  int tid = threadIdx.x;
  if (tid < MM_) {
    idx_s[tid] = e2m[((size_t)b * NE_ + e) * MM_ + tid];
    msk_s[tid] = e2m_mask[((size_t)b * NE_ + e) * MM_ + tid];
  }
  __syncthreads();
  float msum = 0.f;
#pragma unroll
  for (int m = 0; m < MM_; m++) msum += msk_s[m];
  float inv = 1.f / (msum + 1e-7f);
  for (int c = tid; c < EE2; c += 256) {
    const float* base = (c < D_) ? h0 : h1;
    int cc = (c < D_) ? c : c - D_;
    float s = 0.f;
#pragma unroll
    for (int m = 0; m < MM_; m++) {
      int j = idx_s[m];
      if (j > 0) s += base[((size_t)b * N_ + (j - 1)) * D_ + cc] * msk_s[m];
    }
    ent[((size_t)b * NE_ + e) * EE2 + c] = s * inv;
  }
}

// ---------------------------------------------------------------- W1 transpose+convert: W1 (KF x NH fp32) -> W1T (NH x KF bf16)
__global__ __launch_bounds__(256) void k_w1t(const float* __restrict__ W1,
                                             u16* __restrict__ W1T) {
  __shared__ float tile[32][33];
  int k0 = blockIdx.x * 32, n0 = blockIdx.y * 32;
  int tx = threadIdx.x & 31, ty = threadIdx.x >> 5;  // 32 x 8
  for (int i = ty; i < 32; i += 8)
    tile[i][tx] = W1[(size_t)(k0 + i) * NH + n0 + tx];
  __syncthreads();
  for (int i = ty; i < 32; i += 8)
    W1T[(size_t)(n0 + i) * KF + k0 + tx] = f2bf(tile[tx][i]);
}

// ---------------------------------------------------------------- featB: synthesize [hf,tf,|hf-tf|,hf*tf] in bf16
__global__ __launch_bounds__(256) void k_featB(
    const float* __restrict__ ent, const int* __restrict__ ent_pair,
    u16* __restrict__ featB) {
  int row = blockIdx.x;                 // 0..4095
  int b = row >> 10, g = row & 1023;
  int hp = ent_pair[(((size_t)b << 10) + g) * 2 + 0];
  int tp = ent_pair[(((size_t)b << 10) + g) * 2 + 1];
  const float* eh = ent + ((size_t)b * NE_ + hp) * EE2;
  const float* et = ent + ((size_t)b * NE_ + tp) * EE2;
  u16* orow = featB + (size_t)row * KF;
  for (int c = threadIdx.x; c < 1600; c += 256) {  // float4 chunks across all 4 segs
    int seg = c / 400, kk = (c - seg * 400) * 4;
    float4 hf = *(const float4*)(eh + kk);
    float4 tf = *(const float4*)(et + kk);
    float4 v;
    if (seg == 0) v = hf;
    else if (seg == 1) v = tf;
    else if (seg == 2) {
      v.x = fabsf(hf.x - tf.x); v.y = fabsf(hf.y - tf.y);
      v.z = fabsf(hf.z - tf.z); v.w = fabsf(hf.w - tf.w);
    } else {
      v.x = hf.x * tf.x; v.y = hf.y * tf.y;
      v.z = hf.z * tf.z; v.w = hf.w * tf.w;
    }
    ushort4 o;
    o.x = f2bf(v.x); o.y = f2bf(v.y); o.z = f2bf(v.z); o.w = f2bf(v.w);
    *(ushort4*)(orow + seg * 1600 + kk) = o;
  }
}

// ---------------------------------------------------------------- MLP1 bf16 MFMA GEMM
// hidden[4096,3200] = relu(featB[4096,6400] @ W1T^T + b1)
// 128x128 tile, BK=32, 4 waves (2x2 of 64x64), mfma_f32_16x16x32_bf16.
__global__ __launch_bounds__(256) void k_mlp1_mfma(
    const u16* __restrict__ featB, const u16* __restrict__ W1T,
    const float* __restrict__ b1, float* __restrict__ hidden) {
  __shared__ u16 As[128 * 32];
  __shared__ u16 Bs[128 * 32];
  int tid = threadIdx.x;
  int w = tid >> 6, lane = tid & 63;
  int wr = w >> 1, wc = w & 1;
  int lane16 = lane & 15, quad = lane >> 4;
  int n0 = blockIdx.x * 128;
  int m0 = blockIdx.y * 128;

  // staging geometry: tile = 128 rows x 32 cols bf16 = 8192 B = 8 chunks x 1024 B
  int srow = (tid >> 2) & 15;        // lane>>2 within wave handled via chunk
  (void)srow;
  int lrow = lane >> 2;              // 0..15
  int lcol = (lane & 3) * 8;         // ushort offset within 32-col row

  f32x4 acc[4][4] = {};

  const u16* gA = featB + (size_t)m0 * KF;
  const u16* gB = W1T + (size_t)n0 * KF;

  for (int kt = 0; kt < KF; kt += 32) {
    __syncthreads();   // previous compute done before overwrite
#pragma unroll
    for (int j = 0; j < 2; j++) {
      int chunk = j * 4 + w;
      int row = chunk * 16 + lrow;
      __builtin_amdgcn_global_load_lds(
          (const AS1 void*)(gA + (size_t)row * KF + kt + lcol),
          (AS3 void*)(As + chunk * 512 + lane * 8), 16, 0, 0);
      __builtin_amdgcn_global_load_lds(
          (const AS1 void*)(gB + (size_t)row * KF + kt + lcol),
          (AS3 void*)(Bs + chunk * 512 + lane * 8), 16, 0, 0);
    }
    __syncthreads();   // drain loads

    short8 af[4], bf[4];
#pragma unroll
    for (int mi = 0; mi < 4; mi++) {
      int ml = wr * 64 + mi * 16 + lane16;
      af[mi] = *(const short8*)(As + ml * 32 + quad * 8);
    }
#pragma unroll
    for (int ni = 0; ni < 4; ni++) {
      int nl = wc * 64 + ni * 16 + lane16;
      bf[ni] = *(const short8*)(Bs + nl * 32 + quad * 8);
    }
#pragma unroll
    for (int mi = 0; mi < 4; mi++)
#pragma unroll
      for (int ni = 0; ni < 4; ni++)
        acc[mi][ni] = __builtin_amdgcn_mfma_f32_16x16x32_bf16(
            af[mi], bf[ni], acc[mi][ni], 0, 0, 0);
  }

  // epilogue: D layout col=lane&15, row=quad*4+reg
#pragma unroll
  for (int ni = 0; ni < 4; ni++) {
    int col = n0 + wc * 64 + ni * 16 + lane16;
    float bias = b1[col];
#pragma unroll
    for (int mi = 0; mi < 4; mi++) {
      int rbase = m0 + wr * 64 + mi * 16 + quad * 4;
#pragma unroll
      for (int r = 0; r < 4; r++) {
        hidden[(size_t)(rbase + r) * NH + col] =
            fmaxf(acc[mi][ni][r] + bias, 0.f);
      }
    }
  }
}

// ---------------------------------------------------------------- MLP layer2
__global__ __launch_bounds__(128) void k_mlp2(
    const float* __restrict__ hidden, const float* __restrict__ W2,
    const float* __restrict__ b2, float* __restrict__ out) {
  __shared__ float hrow[NH];
  int row = blockIdx.x;
  const float* hr = hidden + (size_t)row * NH;
  for (int i = threadIdx.x; i < NH; i += 128) hrow[i] = hr[i];
  __syncthreads();
  int t = threadIdx.x;
  if (t < OUT_) {
    float acc = b2[t];
#pragma unroll 8
    for (int k = 0; k < NH; k++) acc += hrow[k] * W2[k * OUT_ + t];
    out[(size_t)row * OUT_ + t] = acc;
  }
}

// ----------------------------------------------------------------
extern "C" void kernel_launch(void* const* d_in, const int* in_sizes, int n_in,
                              void* d_out, int out_size, void* d_ws, size_t ws_size,
                              hipStream_t stream) {
  const float* token_feature = (const float*)d_in[0];
  const float* doc_cls       = (const float*)d_in[1];
  const int*   span_pos      = (const int*)d_in[2];
  const float* span_mask     = (const float*)d_in[3];
  const int*   node_ner      = (const int*)d_in[4];
  const float* node_mask     = (const float*)d_in[5];
  const int*   e2m           = (const int*)d_in[6];
  const float* e2m_mask      = (const float*)d_in[7];
  const int*   ent_pair      = (const int*)d_in[8];
  const int*   edge_src      = (const int*)d_in[9];
  const int*   edge_dst      = (const int*)d_in[10];
  const int*   edge_rel      = (const int*)d_in[11];
  const int*   ment_num      = (const int*)d_in[12];
  const float* nerEmb        = (const float*)d_in[13];
  const float* doc_W         = (const float*)d_in[14];
  const float* doc_b         = (const float*)d_in[15];
  const float* W_rel         = (const float*)d_in[16];
  const float* W_self        = (const float*)d_in[17];
  const float* gnn_b         = (const float*)d_in[18];
  const float* W1            = (const float*)d_in[19];
  const float* b1            = (const float*)d_in[20];
  const float* W2            = (const float*)d_in[21];
  const float* b2            = (const float*)d_in[22];
  float* out = (float*)d_out;

  float* ws = (float*)d_ws;
  size_t off = 0;
  auto alloc = [&](size_t n) {
    float* p = ws + off;
    off += (n + 63) & ~size_t(63);
    return p;
  };
  float* doc_proj = alloc(B_ * D_);
  float* x    = alloc((size_t)B_ * N_ * D_);
  float* h0   = alloc((size_t)B_ * N_ * D_);
  float* h1   = alloc((size_t)B_ * N_ * D_);
  float* aggA = alloc((size_t)B_ * N_ * KA);       // 13.1M floats
  float* ent  = alloc((size_t)B_ * NE_ * EE2);
  float* hidden = alloc((size_t)B_ * P_ * NH);
  float* w1t_f  = alloc((size_t)NH * KF / 2);      // 20.48M u16 = 10.24M floats
  u16* W1T   = (u16*)w1t_f;
  u16* featB = (u16*)aggA;                          // alias: aggA dead after GNN
  (void)ws_size;

  // W1 transpose/convert is independent — front-load it.
  k_w1t<<<dim3(KF / 32, NH / 32), 256, 0, stream>>>(W1, W1T);

  k_doc_proj<<<dim3((B_ * D_ + 255) / 256), 256, 0, stream>>>(doc_cls, doc_W, doc_b, doc_proj);
  k_build_node<<<dim3(N_, B_), 256, 0, stream>>>(token_feature, doc_cls, span_pos, span_mask,
                                                 node_ner, node_mask, ment_num, nerEmb,
                                                 doc_proj, x);
  const float* hin = x;
  float* houts[2] = {h0, h1};
  for (int l = 0; l < L_; l++) {
    k_prep<<<dim3(N_, B_), 256, 0, stream>>>(hin, aggA);
    k_scatter<<<dim3(E_, B_), 256, 0, stream>>>(hin, edge_src, edge_dst, edge_rel, aggA);
    k_gnn_gemm<<<dim3(13, 4, B_), 256, 0, stream>>>(aggA, W_rel, W_self, gnn_b, l, houts[l]);
    hin = houts[l];
  }
  k_ent<<<dim3(NE_, B_), 256, 0, stream>>>(h0, h1, e2m, e2m_mask, ent);
  k_featB<<<dim3(B_ * P_), 256, 0, stream>>>(ent, ent_pair, featB);
  k_mlp1_mfma<<<dim3(NH / 128, (B_ * P_) / 128), 256, 0, stream>>>(featB, W1T, b1, hidden);
  k_mlp2<<<dim3(B_ * P_), 128, 0, stream>>>(hidden, W2, b2, out);
}

// Round 3
// 1127.469 us; speedup vs baseline: 4.8749x; 2.8662x over previous
//
#include <hip/hip_runtime.h>
#include <hip/hip_bf16.h>

// Problem dims
#define B_    4
#define T_    512
#define H_    768
#define N_    256
#define S_    16
#define NERD  32
#define D_    800      // H + NER_DIM
#define L_    2
#define R_    15
#define NE_   64
#define MM_   8
#define P_    1024
#define E_    4096
#define OUT_  97
#define NW    12800        // GNN GEMM width: R*D + D  ([W_rel | W_self])
#define EE2   1600         // 2*D
#define KF    (4 * EE2)    // 6400
#define NH    (2 * EE2)    // 3200

typedef unsigned short u16;
typedef unsigned int   u32;
typedef __attribute__((ext_vector_type(8))) short  short8;
typedef __attribute__((ext_vector_type(4))) float  f32x4;

#define AS1 __attribute__((address_space(1)))
#define AS3 __attribute__((address_space(3)))

static __device__ __forceinline__ u16 f2bf(float f) {
  union { float f; u32 u; } v; v.f = f;
  u32 u = v.u;
  u32 r = (u + 0x7FFFu + ((u >> 16) & 1u)) >> 16;  // round-nearest-even
  return (u16)r;
}
static __device__ __forceinline__ float bf2f(u16 h) {
  union { u32 u; float f; } v; v.u = ((u32)h) << 16;
  return v.f;
}

// ---------------------------------------------------------------- doc_proj
__global__ __launch_bounds__(256) void k_doc_proj(
    const float* __restrict__ doc_cls, const float* __restrict__ doc_W,
    const float* __restrict__ doc_b, float* __restrict__ doc_proj) {
  int i = blockIdx.x * 256 + threadIdx.x;
  if (i >= B_ * D_) return;
  int b = i / D_, d = i % D_;
  float acc = doc_b[d];
  const float* dc = doc_cls + b * H_;
#pragma unroll 4
  for (int k = 0; k < H_; k++) acc += dc[k] * doc_W[k * D_ + d];
  doc_proj[i] = fmaxf(acc, 0.f);
}

// ---------------------------------------------------------------- node build -> xB (bf16)
__global__ __launch_bounds__(256) void k_build_node(
    const float* __restrict__ tokf, const float* __restrict__ doc_cls,
    const int* __restrict__ span_pos, const float* __restrict__ span_mask,
    const int* __restrict__ node_ner, const float* __restrict__ node_mask,
    const int* __restrict__ ment_num, const float* __restrict__ nerEmb,
    const float* __restrict__ doc_proj, u16* __restrict__ xB) {
  int n = blockIdx.x, b = blockIdx.y;
  __shared__ int pos_s[S_];
  __shared__ float msk_s[S_];
  int tid = threadIdx.x;
  if (tid < S_) {
    pos_s[tid] = span_pos[((size_t)b * N_ + n) * S_ + tid];
    msk_s[tid] = span_mask[((size_t)b * N_ + n) * S_ + tid];
  }
  __syncthreads();
  float msum = 0.f;
#pragma unroll
  for (int s = 0; s < S_; s++) msum += msk_s[s];
  float rinv = 1.f / (msum + 0.1f);
  int m = ment_num[b];
  float nm = node_mask[b * N_ + n];
  int ner = node_ner[b * N_ + n];
  for (int d = tid; d < D_; d += 256) {
    float v;
    if (d < H_) {
      float ssum = 0.f;
#pragma unroll
      for (int s = 0; s < S_; s++)
        ssum += tokf[((size_t)b * T_ + pos_s[s]) * H_ + d] * msk_s[s];
      v = ssum * rinv + doc_cls[b * H_ + d];
    } else {
      v = nerEmb[ner * NERD + (d - H_)];
    }
    v *= nm;
    if (n == m) v = doc_proj[b * D_ + d];  // x.at[m].set(doc_proj)
    xB[((size_t)b * N_ + n) * D_ + d] = f2bf(v);
  }
}

// ---------------------------------------------------------------- GNN weight transpose:
// WT[l][(i*800+e)][d] = (i<15 ? W_rel[l,i,d,e] : W_self[l,d,e])  (bf16, N x K layout)
__global__ __launch_bounds__(256) void k_wt(const float* __restrict__ W_rel,
                                            const float* __restrict__ W_self,
                                            u16* __restrict__ WT) {
  __shared__ float tile[32][33];
  int l = blockIdx.z >> 4, i = blockIdx.z & 15;
  const float* src = (i < 15) ? (W_rel + ((size_t)l * R_ + i) * D_ * D_)
                              : (W_self + (size_t)l * D_ * D_);
  u16* dst = WT + (size_t)l * NW * D_ + (size_t)i * D_ * D_;
  int d0 = blockIdx.x * 32, e0 = blockIdx.y * 32;
  int tx = threadIdx.x & 31, ty = threadIdx.x >> 5;
  for (int j = ty; j < 32; j += 8)
    tile[j][tx] = src[(size_t)(d0 + j) * D_ + e0 + tx];
  __syncthreads();
  for (int j = ty; j < 32; j += 8)
    dst[(size_t)(e0 + j) * D_ + d0 + tx] = f2bf(tile[tx][j]);
}

// ---------------------------------------------------------------- W1 transpose+convert: W1 (KF x NH fp32) -> W1T (NH x KF bf16)
__global__ __launch_bounds__(256) void k_w1t(const float* __restrict__ W1,
                                             u16* __restrict__ W1T) {
  __shared__ float tile[32][33];
  int k0 = blockIdx.x * 32, n0 = blockIdx.y * 32;
  int tx = threadIdx.x & 31, ty = threadIdx.x >> 5;
  for (int i = ty; i < 32; i += 8)
    tile[i][tx] = W1[(size_t)(k0 + i) * NH + n0 + tx];
  __syncthreads();
  for (int i = ty; i < 32; i += 8)
    W1T[(size_t)(n0 + i) * KF + k0 + tx] = f2bf(tile[tx][i]);
}

// ---------------------------------------------------------------- generic bf16 MFMA GEMM (m97-style)
// C[M x ldc] (bf16) = A[M x KD] @ B[N x KD]^T ; 128x128 tile, BK=32.
template <int KD, bool BIAS_RELU>
__global__ __launch_bounds__(256) void k_gemm_bt(
    const u16* __restrict__ A, const u16* __restrict__ Bm,
    const float* __restrict__ bias, u16* __restrict__ C, int ldc) {
  __shared__ u16 As[128 * 32];
  __shared__ u16 Bs[128 * 32];
  int tid = threadIdx.x;
  int w = tid >> 6, lane = tid & 63;
  int wr = w >> 1, wc = w & 1;
  int lane16 = lane & 15, quad = lane >> 4;
  int n0 = blockIdx.x * 128;
  int m0 = blockIdx.y * 128;

  int lrow = lane >> 2;              // 0..15
  int lcol = (lane & 3) * 8;         // ushort offset within 32-col row

  f32x4 acc[4][4] = {};

  const u16* gA = A + (size_t)m0 * KD;
  const u16* gB = Bm + (size_t)n0 * KD;

  for (int kt = 0; kt < KD; kt += 32) {
    __syncthreads();
#pragma unroll
    for (int j = 0; j < 2; j++) {
      int chunk = j * 4 + w;
      int row = chunk * 16 + lrow;
      __builtin_amdgcn_global_load_lds(
          (const AS1 void*)(gA + (size_t)row * KD + kt + lcol),
          (AS3 void*)(As + chunk * 512 + lane * 8), 16, 0, 0);
      __builtin_amdgcn_global_load_lds(
          (const AS1 void*)(gB + (size_t)row * KD + kt + lcol),
          (AS3 void*)(Bs + chunk * 512 + lane * 8), 16, 0, 0);
    }
    __syncthreads();

    short8 af[4], bf[4];
#pragma unroll
    for (int mi = 0; mi < 4; mi++) {
      int ml = wr * 64 + mi * 16 + lane16;
      af[mi] = *(const short8*)(As + ml * 32 + quad * 8);
    }
#pragma unroll
    for (int ni = 0; ni < 4; ni++) {
      int nl = wc * 64 + ni * 16 + lane16;
      bf[ni] = *(const short8*)(Bs + nl * 32 + quad * 8);
    }
#pragma unroll
    for (int mi = 0; mi < 4; mi++)
#pragma unroll
      for (int ni = 0; ni < 4; ni++)
        acc[mi][ni] = __builtin_amdgcn_mfma_f32_16x16x32_bf16(
            af[mi], bf[ni], acc[mi][ni], 0, 0, 0);
  }

  // epilogue: D layout col=lane&15, row=quad*4+reg
#pragma unroll
  for (int ni = 0; ni < 4; ni++) {
    int col = n0 + wc * 64 + ni * 16 + lane16;
    float bias_v = BIAS_RELU ? bias[col] : 0.f;
#pragma unroll
    for (int mi = 0; mi < 4; mi++) {
      int rbase = m0 + wr * 64 + mi * 16 + quad * 4;
#pragma unroll
      for (int r = 0; r < 4; r++) {
        float v = acc[mi][ni][r];
        if (BIAS_RELU) v = fmaxf(v + bias_v, 0.f);
        C[(size_t)(rbase + r) * ldc + col] = f2bf(v);
      }
    }
  }
}

// ---------------------------------------------------------------- edge aggregation (no atomics on data):
// h_next[b,n] = relu( sum_{e: dst==n} Hr[b,src_e, rel_e*800:..] + Hr[b,n,12000:..] + gnn_b[l] )
__global__ __launch_bounds__(256) void k_agg(
    const u16* __restrict__ Hr, const int* __restrict__ esrc,
    const int* __restrict__ edst, const int* __restrict__ erel,
    const float* __restrict__ gnn_b, int layer,
    float* __restrict__ hout, u16* __restrict__ houtB) {
  int n = blockIdx.x, b = blockIdx.y;
  __shared__ int s_src[E_];
  __shared__ int s_off[E_];   // rel*800 precomputed
  __shared__ int s_cnt;
  int tid = threadIdx.x;
  if (tid == 0) s_cnt = 0;
  __syncthreads();
  const int* dstp = edst + (size_t)b * E_;
  const int* srcp = esrc + (size_t)b * E_;
  const int* relp = erel + (size_t)b * E_;
  for (int e = tid; e < E_; e += 256) {
    if (dstp[e] == n) {
      int i = atomicAdd(&s_cnt, 1);
      s_src[i] = srcp[e];
      s_off[i] = relp[e] * D_;
    }
  }
  __syncthreads();
  int cnt = s_cnt;
  const u16* HrB = Hr + (size_t)b * N_ * NW;
  for (int c = tid; c < D_; c += 256) {
    float acc = bf2f(HrB[(size_t)n * NW + R_ * D_ + c]) + gnn_b[layer * D_ + c];
    for (int i = 0; i < cnt; i++)
      acc += bf2f(HrB[(size_t)s_src[i] * NW + s_off[i] + c]);
    float r = fmaxf(acc, 0.f);
    hout[((size_t)b * N_ + n) * D_ + c] = r;
    houtB[((size_t)b * N_ + n) * D_ + c] = f2bf(r);
  }
}

// ---------------------------------------------------------------- entity mention-mean
__global__ __launch_bounds__(256) void k_ent(
    const float* __restrict__ h0, const float* __restrict__ h1,
    const int* __restrict__ e2m, const float* __restrict__ e2m_mask,
    float* __restrict__ ent) {
  int e = blockIdx.x, b = blockIdx.y;
  __shared__ int idx_s[MM_];
  __shared__ float msk_s[MM_];
  int tid = threadIdx.x;
  if (tid < MM_) {
    idx_s[tid] = e2m[((size_t)b * NE_ + e) * MM_ + tid];
    msk_s[tid] = e2m_mask[((size_t)b * NE_ + e) * MM_ + tid];
  }
  __syncthreads();
  float msum = 0.f;
#pragma unroll
  for (int m = 0; m < MM_; m++) msum += msk_s[m];
  float inv = 1.f / (msum + 1e-7f);
  for (int c = tid; c < EE2; c += 256) {
    const float* base = (c < D_) ? h0 : h1;
    int cc = (c < D_) ? c : c - D_;
    float s = 0.f;
#pragma unroll
    for (int m = 0; m < MM_; m++) {
      int j = idx_s[m];
      if (j > 0) s += base[((size_t)b * N_ + (j - 1)) * D_ + cc] * msk_s[m];
    }
    ent[((size_t)b * NE_ + e) * EE2 + c] = s * inv;
  }
}

// ---------------------------------------------------------------- featB: synthesize [hf,tf,|hf-tf|,hf*tf] in bf16
__global__ __launch_bounds__(256) void k_featB(
    const float* __restrict__ ent, const int* __restrict__ ent_pair,
    u16* __restrict__ featB) {
  int row = blockIdx.x;                 // 0..4095
  int b = row >> 10, g = row & 1023;
  int hp = ent_pair[(((size_t)b << 10) + g) * 2 + 0];
  int tp = ent_pair[(((size_t)b << 10) + g) * 2 + 1];
  const float* eh = ent + ((size_t)b * NE_ + hp) * EE2;
  const float* et = ent + ((size_t)b * NE_ + tp) * EE2;
  u16* orow = featB + (size_t)row * KF;
  for (int c = threadIdx.x; c < 1600; c += 256) {
    int seg = c / 400, kk = (c - seg * 400) * 4;
    float4 hf = *(const float4*)(eh + kk);
    float4 tf = *(const float4*)(et + kk);
    float4 v;
    if (seg == 0) v = hf;
    else if (seg == 1) v = tf;
    else if (seg == 2) {
      v.x = fabsf(hf.x - tf.x); v.y = fabsf(hf.y - tf.y);
      v.z = fabsf(hf.z - tf.z); v.w = fabsf(hf.w - tf.w);
    } else {
      v.x = hf.x * tf.x; v.y = hf.y * tf.y;
      v.z = hf.z * tf.z; v.w = hf.w * tf.w;
    }
    ushort4 o;
    o.x = f2bf(v.x); o.y = f2bf(v.y); o.z = f2bf(v.z); o.w = f2bf(v.w);
    *(ushort4*)(orow + seg * 1600 + kk) = o;
  }
}

// ---------------------------------------------------------------- MLP layer2 (reads bf16 hidden)
__global__ __launch_bounds__(128) void k_mlp2(
    const u16* __restrict__ hiddenB, const float* __restrict__ W2,
    const float* __restrict__ b2, float* __restrict__ out) {
  __shared__ float hrow[NH];
  int row = blockIdx.x;
  const u16* hr = hiddenB + (size_t)row * NH;
  for (int i = threadIdx.x; i < NH; i += 128) hrow[i] = bf2f(hr[i]);
  __syncthreads();
  int t = threadIdx.x;
  if (t < OUT_) {
    float acc = b2[t];
#pragma unroll 8
    for (int k = 0; k < NH; k++) acc += hrow[k] * W2[k * OUT_ + t];
    out[(size_t)row * OUT_ + t] = acc;
  }
}

// ----------------------------------------------------------------
extern "C" void kernel_launch(void* const* d_in, const int* in_sizes, int n_in,
                              void* d_out, int out_size, void* d_ws, size_t ws_size,
                              hipStream_t stream) {
  const float* token_feature = (const float*)d_in[0];
  const float* doc_cls       = (const float*)d_in[1];
  const int*   span_pos      = (const int*)d_in[2];
  const float* span_mask     = (const float*)d_in[3];
  const int*   node_ner      = (const int*)d_in[4];
  const float* node_mask     = (const float*)d_in[5];
  const int*   e2m           = (const int*)d_in[6];
  const float* e2m_mask      = (const float*)d_in[7];
  const int*   ent_pair      = (const int*)d_in[8];
  const int*   edge_src      = (const int*)d_in[9];
  const int*   edge_dst      = (const int*)d_in[10];
  const int*   edge_rel      = (const int*)d_in[11];
  const int*   ment_num      = (const int*)d_in[12];
  const float* nerEmb        = (const float*)d_in[13];
  const float* doc_W         = (const float*)d_in[14];
  const float* doc_b         = (const float*)d_in[15];
  const float* W_rel         = (const float*)d_in[16];
  const float* W_self        = (const float*)d_in[17];
  const float* gnn_b         = (const float*)d_in[18];
  const float* W1            = (const float*)d_in[19];
  const float* b1            = (const float*)d_in[20];
  const float* W2            = (const float*)d_in[21];
  const float* b2            = (const float*)d_in[22];
  float* out = (float*)d_out;

  float* ws = (float*)d_ws;
  size_t off = 0;
  auto alloc = [&](size_t n) {
    float* p = ws + off;
    off += (n + 63) & ~size_t(63);
    return p;
  };
  float* doc_proj = alloc(B_ * D_);
  u16*   xB  = (u16*)alloc((size_t)B_ * N_ * D_ / 2);
  float* h0  = alloc((size_t)B_ * N_ * D_);
  float* h1  = alloc((size_t)B_ * N_ * D_);
  u16*   hB  = (u16*)alloc((size_t)B_ * N_ * D_ / 2);
  float* ent = alloc((size_t)B_ * NE_ * EE2);
  u16*   WT  = (u16*)alloc((size_t)L_ * NW * D_ / 2);
  u16*   W1T = (u16*)alloc((size_t)NH * KF / 2);
  // R1: Hr (26.2 MB) then featB (52.4 MB) — Hr dead before featB is written
  float* R1  = alloc((size_t)B_ * P_ * KF / 2);
  u16*   Hr    = (u16*)R1;
  u16*   featB = (u16*)R1;
  u16*   hiddenB = (u16*)alloc((size_t)B_ * P_ * NH / 2);
  (void)ws_size;

  // front-load weight prep (independent of data path)
  k_wt<<<dim3(D_ / 32, D_ / 32, L_ * 16), 256, 0, stream>>>(W_rel, W_self, WT);
  k_w1t<<<dim3(KF / 32, NH / 32), 256, 0, stream>>>(W1, W1T);

  k_doc_proj<<<dim3((B_ * D_ + 255) / 256), 256, 0, stream>>>(doc_cls, doc_W, doc_b, doc_proj);
  k_build_node<<<dim3(N_, B_), 256, 0, stream>>>(token_feature, doc_cls, span_pos, span_mask,
                                                 node_ner, node_mask, ment_num, nerEmb,
                                                 doc_proj, xB);
  // GNN layers: Hr = h @ [W_rel|W_self]^T  then edge-gather aggregate
  const u16* hin = xB;
  float* houts[2] = {h0, h1};
  for (int l = 0; l < L_; l++) {
    k_gemm_bt<D_, false><<<dim3(NW / 128, (B_ * N_) / 128), 256, 0, stream>>>(
        hin, WT + (size_t)l * NW * D_, nullptr, Hr, NW);
    k_agg<<<dim3(N_, B_), 256, 0, stream>>>(Hr, edge_src, edge_dst, edge_rel,
                                            gnn_b, l, houts[l], hB);
    hin = hB;
  }
  k_ent<<<dim3(NE_, B_), 256, 0, stream>>>(h0, h1, e2m, e2m_mask, ent);
  k_featB<<<dim3(B_ * P_), 256, 0, stream>>>(ent, ent_pair, featB);
  k_gemm_bt<KF, true><<<dim3(NH / 128, (B_ * P_) / 128), 256, 0, stream>>>(
      featB, W1T, b1, hiddenB, NH);
  k_mlp2<<<dim3(B_ * P_), 128, 0, stream>>>(hiddenB, W2, b2, out);
}

// Round 4
// 829.557 us; speedup vs baseline: 6.6255x; 1.3591x over previous
//
#include <hip/hip_runtime.h>
#include <hip/hip_bf16.h>

// Problem dims
#define B_    4
#define T_    512
#define H_    768
#define N_    256
#define S_    16
#define NERD  32
#define D_    800      // H + NER_DIM
#define L_    2
#define R_    15
#define NE_   64
#define MM_   8
#define P_    1024
#define E_    4096
#define OUT_  97
#define NW    12800        // GNN GEMM width: R*D + D  ([W_rel | W_self])
#define EE2   1600         // 2*D
#define KF    (4 * EE2)    // 6400
#define NH    (2 * EE2)    // 3200

typedef unsigned short u16;
typedef unsigned int   u32;
typedef __attribute__((ext_vector_type(8))) short  short8;
typedef __attribute__((ext_vector_type(4))) float  f32x4;

#define AS1 __attribute__((address_space(1)))
#define AS3 __attribute__((address_space(3)))

static __device__ __forceinline__ u16 f2bf(float f) {
  union { float f; u32 u; } v; v.f = f;
  u32 u = v.u;
  u32 r = (u + 0x7FFFu + ((u >> 16) & 1u)) >> 16;  // round-nearest-even
  return (u16)r;
}
static __device__ __forceinline__ float bf2f(u16 h) {
  union { u32 u; float f; } v; v.u = ((u32)h) << 16;
  return v.f;
}

// ---------------------------------------------------------------- doc_proj
__global__ __launch_bounds__(256) void k_doc_proj(
    const float* __restrict__ doc_cls, const float* __restrict__ doc_W,
    const float* __restrict__ doc_b, float* __restrict__ doc_proj) {
  int i = blockIdx.x * 256 + threadIdx.x;
  if (i >= B_ * D_) return;
  int b = i / D_, d = i % D_;
  float acc = doc_b[d];
  const float* dc = doc_cls + b * H_;
#pragma unroll 4
  for (int k = 0; k < H_; k++) acc += dc[k] * doc_W[k * D_ + d];
  doc_proj[i] = fmaxf(acc, 0.f);
}

// ---------------------------------------------------------------- node build -> xB (bf16)
__global__ __launch_bounds__(256) void k_build_node(
    const float* __restrict__ tokf, const float* __restrict__ doc_cls,
    const int* __restrict__ span_pos, const float* __restrict__ span_mask,
    const int* __restrict__ node_ner, const float* __restrict__ node_mask,
    const int* __restrict__ ment_num, const float* __restrict__ nerEmb,
    const float* __restrict__ doc_proj, u16* __restrict__ xB) {
  int n = blockIdx.x, b = blockIdx.y;
  __shared__ int pos_s[S_];
  __shared__ float msk_s[S_];
  int tid = threadIdx.x;
  if (tid < S_) {
    pos_s[tid] = span_pos[((size_t)b * N_ + n) * S_ + tid];
    msk_s[tid] = span_mask[((size_t)b * N_ + n) * S_ + tid];
  }
  __syncthreads();
  float msum = 0.f;
#pragma unroll
  for (int s = 0; s < S_; s++) msum += msk_s[s];
  float rinv = 1.f / (msum + 0.1f);
  int m = ment_num[b];
  float nm = node_mask[b * N_ + n];
  int ner = node_ner[b * N_ + n];
  for (int d = tid; d < D_; d += 256) {
    float v;
    if (d < H_) {
      float ssum = 0.f;
#pragma unroll
      for (int s = 0; s < S_; s++)
        ssum += tokf[((size_t)b * T_ + pos_s[s]) * H_ + d] * msk_s[s];
      v = ssum * rinv + doc_cls[b * H_ + d];
    } else {
      v = nerEmb[ner * NERD + (d - H_)];
    }
    v *= nm;
    if (n == m) v = doc_proj[b * D_ + d];
    xB[((size_t)b * N_ + n) * D_ + d] = f2bf(v);
  }
}

// ---------------------------------------------------------------- GNN weight transpose
__global__ __launch_bounds__(256) void k_wt(const float* __restrict__ W_rel,
                                            const float* __restrict__ W_self,
                                            u16* __restrict__ WT) {
  __shared__ float tile[32][33];
  int l = blockIdx.z >> 4, i = blockIdx.z & 15;
  const float* src = (i < 15) ? (W_rel + ((size_t)l * R_ + i) * D_ * D_)
                              : (W_self + (size_t)l * D_ * D_);
  u16* dst = WT + (size_t)l * NW * D_ + (size_t)i * D_ * D_;
  int d0 = blockIdx.x * 32, e0 = blockIdx.y * 32;
  int tx = threadIdx.x & 31, ty = threadIdx.x >> 5;
  for (int j = ty; j < 32; j += 8)
    tile[j][tx] = src[(size_t)(d0 + j) * D_ + e0 + tx];
  __syncthreads();
  for (int j = ty; j < 32; j += 8)
    dst[(size_t)(e0 + j) * D_ + d0 + tx] = f2bf(tile[tx][j]);
}

// ---------------------------------------------------------------- W1 transpose: W1 (KF x NH fp32) -> W1T (NH x KF bf16)
__global__ __launch_bounds__(256) void k_w1t(const float* __restrict__ W1,
                                             u16* __restrict__ W1T) {
  __shared__ float tile[32][33];
  int k0 = blockIdx.x * 32, n0 = blockIdx.y * 32;
  int tx = threadIdx.x & 31, ty = threadIdx.x >> 5;
  for (int i = ty; i < 32; i += 8)
    tile[i][tx] = W1[(size_t)(k0 + i) * NH + n0 + tx];
  __syncthreads();
  for (int i = ty; i < 32; i += 8)
    W1T[(size_t)(n0 + i) * KF + k0 + tx] = f2bf(tile[tx][i]);
}

// ---------------------------------------------------------------- W2 transpose: W2 (NH x 97 fp32) -> W2T (128 x NH bf16), pad rows zero
__global__ __launch_bounds__(256) void k_w2t(const float* __restrict__ W2,
                                             u16* __restrict__ W2T) {
  __shared__ float tile[32][33];
  int k0 = blockIdx.x * 32, n0 = blockIdx.y * 32;
  int tx = threadIdx.x & 31, ty = threadIdx.x >> 5;
  for (int i = ty; i < 32; i += 8)
    tile[i][tx] = (n0 + tx < OUT_) ? W2[(size_t)(k0 + i) * OUT_ + n0 + tx] : 0.f;
  __syncthreads();
  for (int i = ty; i < 32; i += 8)
    W2T[(size_t)(n0 + i) * NH + k0 + tx] = f2bf(tile[tx][i]);
}

// ---------------------------------------------------------------- generic bf16 MFMA GEMM (m97-style)
// C[...] = A[M x K](lda) @ B[N x K](ldb)^T ; 128x128 tile, BK=32, group-M swizzle.
// EPI: 0 = bf16 plain, 1 = f32 plain, 2 = bf16 relu(acc+bias+preA[hp]+preB[tp]), 3 = f32 acc+bias, col<OUT_
template <int KD, int EPI>
__global__ __launch_bounds__(256) void k_gemm_bt(
    const u16* __restrict__ A, int lda, const u16* __restrict__ Bm, int ldb,
    const float* __restrict__ bias, const float* __restrict__ preA,
    const float* __restrict__ preB, const int* __restrict__ pairs,
    void* __restrict__ Cv, int ldc) {
  __shared__ u16 As[128 * 32];
  __shared__ u16 Bs[128 * 32];
  int tid = threadIdx.x;
  int w = tid >> 6, lane = tid & 63;
  int wr = w >> 1, wc = w & 1;
  int lane16 = lane & 15, quad = lane >> 4;

  // group-M swizzle for L2 locality
  int nbn = gridDim.x, nbm = gridDim.y;
  int pid = blockIdx.y * nbn + blockIdx.x;
  const int GROUP = 8;
  int npg = GROUP * nbn;
  int gidg = pid / npg;
  int first = gidg * GROUP;
  int szm = min(nbm - first, GROUP);
  int pid_m = first + (pid % npg) % szm;
  int pid_n = (pid % npg) / szm;
  int n0 = pid_n * 128;
  int m0 = pid_m * 128;

  int lrow = lane >> 2;              // 0..15
  int lcol = (lane & 3) * 8;         // ushort offset within 32-col row

  f32x4 acc[4][4] = {};

  const u16* gA = A + (size_t)m0 * lda;
  const u16* gB = Bm + (size_t)n0 * ldb;

  for (int kt = 0; kt < KD; kt += 32) {
    __syncthreads();
#pragma unroll
    for (int j = 0; j < 2; j++) {
      int chunk = j * 4 + w;
      int row = chunk * 16 + lrow;
      __builtin_amdgcn_global_load_lds(
          (const AS1 void*)(gA + (size_t)row * lda + kt + lcol),
          (AS3 void*)(As + chunk * 512 + lane * 8), 16, 0, 0);
      __builtin_amdgcn_global_load_lds(
          (const AS1 void*)(gB + (size_t)row * ldb + kt + lcol),
          (AS3 void*)(Bs + chunk * 512 + lane * 8), 16, 0, 0);
    }
    __syncthreads();

    short8 af[4], bf[4];
#pragma unroll
    for (int mi = 0; mi < 4; mi++) {
      int ml = wr * 64 + mi * 16 + lane16;
      af[mi] = *(const short8*)(As + ml * 32 + quad * 8);
    }
#pragma unroll
    for (int ni = 0; ni < 4; ni++) {
      int nl = wc * 64 + ni * 16 + lane16;
      bf[ni] = *(const short8*)(Bs + nl * 32 + quad * 8);
    }
#pragma unroll
    for (int mi = 0; mi < 4; mi++)
#pragma unroll
      for (int ni = 0; ni < 4; ni++)
        acc[mi][ni] = __builtin_amdgcn_mfma_f32_16x16x32_bf16(
            af[mi], bf[ni], acc[mi][ni], 0, 0, 0);
  }

  // epilogue: D layout col=lane&15, row=quad*4+reg
  int cols[4];
  float bv[4];
#pragma unroll
  for (int ni = 0; ni < 4; ni++) {
    cols[ni] = n0 + wc * 64 + ni * 16 + lane16;
    if (EPI == 2) bv[ni] = bias[cols[ni]];
    if (EPI == 3) bv[ni] = (cols[ni] < OUT_) ? bias[cols[ni]] : 0.f;
  }
#pragma unroll
  for (int mi = 0; mi < 4; mi++) {
#pragma unroll
    for (int r = 0; r < 4; r++) {
      int row = m0 + wr * 64 + mi * 16 + quad * 4 + r;
      const float* pAr = nullptr;
      const float* pBr = nullptr;
      if (EPI == 2) {
        int hp = pairs[2 * row], tp = pairs[2 * row + 1];
        int pb = (row >> 10) * NE_;
        pAr = preA + (size_t)(pb + hp) * NH;
        pBr = preB + (size_t)(pb + tp) * NH;
      }
#pragma unroll
      for (int ni = 0; ni < 4; ni++) {
        float v = acc[mi][ni][r];
        int col = cols[ni];
        if (EPI == 0) {
          ((u16*)Cv)[(size_t)row * ldc + col] = f2bf(v);
        } else if (EPI == 1) {
          ((float*)Cv)[(size_t)row * ldc + col] = v;
        } else if (EPI == 2) {
          v += bv[ni] + pAr[col] + pBr[col];
          ((u16*)Cv)[(size_t)row * ldc + col] = f2bf(fmaxf(v, 0.f));
        } else {
          if (col < OUT_)
            ((float*)Cv)[(size_t)row * ldc + col] = v + bv[ni];
        }
      }
    }
  }
}

// ---------------------------------------------------------------- edge aggregation
__global__ __launch_bounds__(256) void k_agg(
    const u16* __restrict__ Hr, const int* __restrict__ esrc,
    const int* __restrict__ edst, const int* __restrict__ erel,
    const float* __restrict__ gnn_b, int layer,
    float* __restrict__ hout, u16* __restrict__ houtB) {
  int n = blockIdx.x, b = blockIdx.y;
  __shared__ int s_pk[E_];   // src | (rel<<9)
  __shared__ int s_cnt;
  int tid = threadIdx.x;
  if (tid == 0) s_cnt = 0;
  __syncthreads();
  const int* dstp = edst + (size_t)b * E_;
  const int* srcp = esrc + (size_t)b * E_;
  const int* relp = erel + (size_t)b * E_;
  for (int e = tid; e < E_; e += 256) {
    if (dstp[e] == n) {
      int i = atomicAdd(&s_cnt, 1);
      s_pk[i] = srcp[e] | (relp[e] << 9);
    }
  }
  __syncthreads();
  int cnt = s_cnt;
  const u16* HrB = Hr + (size_t)b * N_ * NW;
  for (int c = tid; c < D_; c += 256) {
    float acc = bf2f(HrB[(size_t)n * NW + R_ * D_ + c]) + gnn_b[layer * D_ + c];
    for (int i = 0; i < cnt; i++) {
      int pk = s_pk[i];
      acc += bf2f(HrB[(size_t)(pk & 511) * NW + (pk >> 9) * D_ + c]);
    }
    float r = fmaxf(acc, 0.f);
    hout[((size_t)b * N_ + n) * D_ + c] = r;
    houtB[((size_t)b * N_ + n) * D_ + c] = f2bf(r);
  }
}

// ---------------------------------------------------------------- entity mention-mean (f32 + bf16 out)
__global__ __launch_bounds__(256) void k_ent(
    const float* __restrict__ h0, const float* __restrict__ h1,
    const int* __restrict__ e2m, const float* __restrict__ e2m_mask,
    float* __restrict__ ent, u16* __restrict__ entB) {
  int e = blockIdx.x, b = blockIdx.y;
  __shared__ int idx_s[MM_];
  __shared__ float msk_s[MM_];
  int tid = threadIdx.x;
  if (tid < MM_) {
    idx_s[tid] = e2m[((size_t)b * NE_ + e) * MM_ + tid];
    msk_s[tid] = e2m_mask[((size_t)b * NE_ + e) * MM_ + tid];
  }
  __syncthreads();
  float msum = 0.f;
#pragma unroll
  for (int m = 0; m < MM_; m++) msum += msk_s[m];
  float inv = 1.f / (msum + 1e-7f);
  for (int c = tid; c < EE2; c += 256) {
    const float* base = (c < D_) ? h0 : h1;
    int cc = (c < D_) ? c : c - D_;
    float s = 0.f;
#pragma unroll
    for (int m = 0; m < MM_; m++) {
      int j = idx_s[m];
      if (j > 0) s += base[((size_t)b * N_ + (j - 1)) * D_ + cc] * msk_s[m];
    }
    float v = s * inv;
    ent[((size_t)b * NE_ + e) * EE2 + c] = v;
    entB[((size_t)b * NE_ + e) * EE2 + c] = f2bf(v);
  }
}

// ---------------------------------------------------------------- featC: [|hf-tf|, hf*tf] bf16 (4096 x 3200)
__global__ __launch_bounds__(256) void k_featC(
    const float* __restrict__ ent, const int* __restrict__ ent_pair,
    u16* __restrict__ featC) {
  int row = blockIdx.x;                 // 0..4095
  int b = row >> 10, g = row & 1023;
  int hp = ent_pair[(((size_t)b << 10) + g) * 2 + 0];
  int tp = ent_pair[(((size_t)b << 10) + g) * 2 + 1];
  const float* eh = ent + ((size_t)b * NE_ + hp) * EE2;
  const float* et = ent + ((size_t)b * NE_ + tp) * EE2;
  u16* orow = featC + (size_t)row * NH;
  for (int c = threadIdx.x; c < 800; c += 256) {   // float4 chunks, 2 segs
    int seg = c / 400, kk = (c - seg * 400) * 4;
    float4 hf = *(const float4*)(eh + kk);
    float4 tf = *(const float4*)(et + kk);
    float4 v;
    if (seg == 0) {
      v.x = fabsf(hf.x - tf.x); v.y = fabsf(hf.y - tf.y);
      v.z = fabsf(hf.z - tf.z); v.w = fabsf(hf.w - tf.w);
    } else {
      v.x = hf.x * tf.x; v.y = hf.y * tf.y;
      v.z = hf.z * tf.z; v.w = hf.w * tf.w;
    }
    ushort4 o;
    o.x = f2bf(v.x); o.y = f2bf(v.y); o.z = f2bf(v.z); o.w = f2bf(v.w);
    *(ushort4*)(orow + seg * EE2 + kk) = o;
  }
}

// ----------------------------------------------------------------
extern "C" void kernel_launch(void* const* d_in, const int* in_sizes, int n_in,
                              void* d_out, int out_size, void* d_ws, size_t ws_size,
                              hipStream_t stream) {
  const float* token_feature = (const float*)d_in[0];
  const float* doc_cls       = (const float*)d_in[1];
  const int*   span_pos      = (const int*)d_in[2];
  const float* span_mask     = (const float*)d_in[3];
  const int*   node_ner      = (const int*)d_in[4];
  const float* node_mask     = (const float*)d_in[5];
  const int*   e2m           = (const int*)d_in[6];
  const float* e2m_mask      = (const float*)d_in[7];
  const int*   ent_pair      = (const int*)d_in[8];
  const int*   edge_src      = (const int*)d_in[9];
  const int*   edge_dst      = (const int*)d_in[10];
  const int*   edge_rel      = (const int*)d_in[11];
  const int*   ment_num      = (const int*)d_in[12];
  const float* nerEmb        = (const float*)d_in[13];
  const float* doc_W         = (const float*)d_in[14];
  const float* doc_b         = (const float*)d_in[15];
  const float* W_rel         = (const float*)d_in[16];
  const float* W_self        = (const float*)d_in[17];
  const float* gnn_b         = (const float*)d_in[18];
  const float* W1            = (const float*)d_in[19];
  const float* b1            = (const float*)d_in[20];
  const float* W2            = (const float*)d_in[21];
  const float* b2            = (const float*)d_in[22];
  float* out = (float*)d_out;

  float* ws = (float*)d_ws;
  size_t off = 0;
  auto alloc = [&](size_t n) {
    float* p = ws + off;
    off += (n + 63) & ~size_t(63);
    return p;
  };
  float* doc_proj = alloc(B_ * D_);
  u16*   xB  = (u16*)alloc((size_t)B_ * N_ * D_ / 2);
  float* h0  = alloc((size_t)B_ * N_ * D_);
  float* h1  = alloc((size_t)B_ * N_ * D_);
  u16*   hB  = (u16*)alloc((size_t)B_ * N_ * D_ / 2);
  float* ent = alloc((size_t)B_ * NE_ * EE2);
  u16*   entB = (u16*)alloc((size_t)B_ * NE_ * EE2 / 2);
  u16*   WT  = (u16*)alloc((size_t)L_ * NW * D_ / 2);
  u16*   W1T = (u16*)alloc((size_t)NH * KF / 2);
  u16*   W2T = (u16*)alloc((size_t)128 * NH / 2);
  float* preA = alloc((size_t)B_ * NE_ * NH);
  float* preB = alloc((size_t)B_ * NE_ * NH);
  // Hr (1024x12800 u16) and featC (4096x3200 u16) are the same size; Hr dead after agg
  u16*   Hr    = (u16*)alloc((size_t)B_ * N_ * NW / 2);
  u16*   featC = Hr;
  u16*   hiddenB = (u16*)alloc((size_t)B_ * P_ * NH / 2);
  (void)ws_size;

  // front-load weight prep (independent of data path)
  k_wt<<<dim3(D_ / 32, D_ / 32, L_ * 16), 256, 0, stream>>>(W_rel, W_self, WT);
  k_w1t<<<dim3(KF / 32, NH / 32), 256, 0, stream>>>(W1, W1T);
  k_w2t<<<dim3(NH / 32, 4), 256, 0, stream>>>(W2, W2T);

  k_doc_proj<<<dim3((B_ * D_ + 255) / 256), 256, 0, stream>>>(doc_cls, doc_W, doc_b, doc_proj);
  k_build_node<<<dim3(N_, B_), 256, 0, stream>>>(token_feature, doc_cls, span_pos, span_mask,
                                                 node_ner, node_mask, ment_num, nerEmb,
                                                 doc_proj, xB);
  // GNN layers
  const u16* hin = xB;
  float* houts[2] = {h0, h1};
  for (int l = 0; l < L_; l++) {
    k_gemm_bt<D_, 0><<<dim3(NW / 128, (B_ * N_) / 128), 256, 0, stream>>>(
        hin, D_, WT + (size_t)l * NW * D_, D_, nullptr, nullptr, nullptr, nullptr,
        Hr, NW);
    k_agg<<<dim3(N_, B_), 256, 0, stream>>>(Hr, edge_src, edge_dst, edge_rel,
                                            gnn_b, l, houts[l], hB);
    hin = hB;
  }
  k_ent<<<dim3(NE_, B_), 256, 0, stream>>>(h0, h1, e2m, e2m_mask, ent, entB);

  // pre GEMMs: preA = ent @ W1a, preB = ent @ W1b   (M=256, K=1600, N=3200)
  k_gemm_bt<EE2, 1><<<dim3(NH / 128, (B_ * NE_) / 128), 256, 0, stream>>>(
      entB, EE2, W1T, KF, nullptr, nullptr, nullptr, nullptr, preA, NH);
  k_gemm_bt<EE2, 1><<<dim3(NH / 128, (B_ * NE_) / 128), 256, 0, stream>>>(
      entB, EE2, W1T + EE2, KF, nullptr, nullptr, nullptr, nullptr, preB, NH);

  k_featC<<<dim3(B_ * P_), 256, 0, stream>>>(ent, ent_pair, featC);

  // big GEMM: hidden = relu(featC @ W1cd^T + preA[hp] + preB[tp] + b1)
  k_gemm_bt<NH, 2><<<dim3(NH / 128, (B_ * P_) / 128), 256, 0, stream>>>(
      featC, NH, W1T + 2 * EE2, KF, b1, preA, preB, ent_pair, hiddenB, NH);

  // mlp2: out = hiddenB @ W2T^T + b2  (N padded to 128, store col<97)
  k_gemm_bt<NH, 3><<<dim3(1, (B_ * P_) / 128), 256, 0, stream>>>(
      hiddenB, NH, W2T, NH, b2, nullptr, nullptr, nullptr, out, OUT_);
}

// Round 5
// 783.904 us; speedup vs baseline: 7.0114x; 1.0582x over previous
//
#include <hip/hip_runtime.h>
#include <hip/hip_bf16.h>

// Problem dims
#define B_    4
#define T_    512
#define H_    768
#define N_    256
#define S_    16
#define NERD  32
#define D_    800      // H + NER_DIM
#define L_    2
#define R_    15
#define NE_   64
#define MM_   8
#define P_    1024
#define E_    4096
#define OUT_  97
#define NW    12800        // GNN GEMM width: R*D + D  ([W_rel | W_self])
#define EE2   1600         // 2*D
#define KF    (4 * EE2)    // 6400
#define NH    (2 * EE2)    // 3200
#define KS    800          // mlp2 K-split slice
#define NZ    4            // mlp2 K-split count

typedef unsigned short u16;
typedef unsigned int   u32;
typedef __attribute__((ext_vector_type(8))) short  short8;
typedef __attribute__((ext_vector_type(4))) float  f32x4;

#define AS1 __attribute__((address_space(1)))
#define AS3 __attribute__((address_space(3)))

static __device__ __forceinline__ u16 f2bf(float f) {
  union { float f; u32 u; } v; v.f = f;
  u32 u = v.u;
  u32 r = (u + 0x7FFFu + ((u >> 16) & 1u)) >> 16;  // round-nearest-even
  return (u16)r;
}
static __device__ __forceinline__ float bf2f(u16 h) {
  union { u32 u; float f; } v; v.u = ((u32)h) << 16;
  return v.f;
}

// ---------------------------------------------------------------- doc_proj
__global__ __launch_bounds__(256) void k_doc_proj(
    const float* __restrict__ doc_cls, const float* __restrict__ doc_W,
    const float* __restrict__ doc_b, float* __restrict__ doc_proj) {
  int i = blockIdx.x * 256 + threadIdx.x;
  if (i >= B_ * D_) return;
  int b = i / D_, d = i % D_;
  float acc = doc_b[d];
  const float* dc = doc_cls + b * H_;
#pragma unroll 4
  for (int k = 0; k < H_; k++) acc += dc[k] * doc_W[k * D_ + d];
  doc_proj[i] = fmaxf(acc, 0.f);
}

// ---------------------------------------------------------------- node build -> xB (bf16)
__global__ __launch_bounds__(256) void k_build_node(
    const float* __restrict__ tokf, const float* __restrict__ doc_cls,
    const int* __restrict__ span_pos, const float* __restrict__ span_mask,
    const int* __restrict__ node_ner, const float* __restrict__ node_mask,
    const int* __restrict__ ment_num, const float* __restrict__ nerEmb,
    const float* __restrict__ doc_proj, u16* __restrict__ xB) {
  int n = blockIdx.x, b = blockIdx.y;
  __shared__ int pos_s[S_];
  __shared__ float msk_s[S_];
  int tid = threadIdx.x;
  if (tid < S_) {
    pos_s[tid] = span_pos[((size_t)b * N_ + n) * S_ + tid];
    msk_s[tid] = span_mask[((size_t)b * N_ + n) * S_ + tid];
  }
  __syncthreads();
  float msum = 0.f;
#pragma unroll
  for (int s = 0; s < S_; s++) msum += msk_s[s];
  float rinv = 1.f / (msum + 0.1f);
  int m = ment_num[b];
  float nm = node_mask[b * N_ + n];
  int ner = node_ner[b * N_ + n];
  for (int d = tid; d < D_; d += 256) {
    float v;
    if (d < H_) {
      float ssum = 0.f;
#pragma unroll
      for (int s = 0; s < S_; s++)
        ssum += tokf[((size_t)b * T_ + pos_s[s]) * H_ + d] * msk_s[s];
      v = ssum * rinv + doc_cls[b * H_ + d];
    } else {
      v = nerEmb[ner * NERD + (d - H_)];
    }
    v *= nm;
    if (n == m) v = doc_proj[b * D_ + d];
    xB[((size_t)b * N_ + n) * D_ + d] = f2bf(v);
  }
}

// ---------------------------------------------------------------- GNN weight transpose
__global__ __launch_bounds__(256) void k_wt(const float* __restrict__ W_rel,
                                            const float* __restrict__ W_self,
                                            u16* __restrict__ WT) {
  __shared__ float tile[32][33];
  int l = blockIdx.z >> 4, i = blockIdx.z & 15;
  const float* src = (i < 15) ? (W_rel + ((size_t)l * R_ + i) * D_ * D_)
                              : (W_self + (size_t)l * D_ * D_);
  u16* dst = WT + (size_t)l * NW * D_ + (size_t)i * D_ * D_;
  int d0 = blockIdx.x * 32, e0 = blockIdx.y * 32;
  int tx = threadIdx.x & 31, ty = threadIdx.x >> 5;
  for (int j = ty; j < 32; j += 8)
    tile[j][tx] = src[(size_t)(d0 + j) * D_ + e0 + tx];
  __syncthreads();
  for (int j = ty; j < 32; j += 8)
    dst[(size_t)(e0 + j) * D_ + d0 + tx] = f2bf(tile[tx][j]);
}

// ---------------------------------------------------------------- W1 transpose:
// W1 (KF x NH fp32) ->  W1abT (6400 x 1600 bf16)  rows: n for a-part, 3200+n for b-part
//                       W1cdT (3200 x 3200 bf16)  rows: n, k = kcol-3200
__global__ __launch_bounds__(256) void k_w1t(const float* __restrict__ W1,
                                             u16* __restrict__ W1abT,
                                             u16* __restrict__ W1cdT) {
  __shared__ float tile[32][33];
  int k0 = blockIdx.x * 32, n0 = blockIdx.y * 32;
  int tx = threadIdx.x & 31, ty = threadIdx.x >> 5;
  for (int i = ty; i < 32; i += 8)
    tile[i][tx] = W1[(size_t)(k0 + i) * NH + n0 + tx];
  __syncthreads();
  for (int i = ty; i < 32; i += 8) {
    int kk = k0 + tx, n = n0 + i;
    u16 v = f2bf(tile[tx][i]);
    if (kk < EE2)            W1abT[(size_t)n * EE2 + kk] = v;
    else if (kk < 2 * EE2)   W1abT[(size_t)(NH + n) * EE2 + (kk - EE2)] = v;
    else                     W1cdT[(size_t)n * NH + (kk - 2 * EE2)] = v;
  }
}

// ---------------------------------------------------------------- W2 transpose: W2 (NH x 97 fp32) -> W2T (128 x NH bf16), pad rows zero
__global__ __launch_bounds__(256) void k_w2t(const float* __restrict__ W2,
                                             u16* __restrict__ W2T) {
  __shared__ float tile[32][33];
  int k0 = blockIdx.x * 32, n0 = blockIdx.y * 32;
  int tx = threadIdx.x & 31, ty = threadIdx.x >> 5;
  for (int i = ty; i < 32; i += 8)
    tile[i][tx] = (n0 + tx < OUT_) ? W2[(size_t)(k0 + i) * OUT_ + n0 + tx] : 0.f;
  __syncthreads();
  for (int i = ty; i < 32; i += 8)
    W2T[(size_t)(n0 + i) * NH + k0 + tx] = f2bf(tile[tx][i]);
}

// ---------------------------------------------------------------- CSR build (edge lists, built once, used by both agg layers)
__global__ __launch_bounds__(256) void k_csr_zero(int* __restrict__ cnt) {
  cnt[blockIdx.x * 256 + threadIdx.x] = 0;
}
__global__ __launch_bounds__(256) void k_csr_count(const int* __restrict__ edst,
                                                   int* __restrict__ cnt) {
  int e = blockIdx.x * 256 + threadIdx.x, b = blockIdx.y;
  atomicAdd(&cnt[b * N_ + edst[(size_t)b * E_ + e]], 1);
}
__global__ __launch_bounds__(256) void k_csr_scan(const int* __restrict__ cnt,
                                                  int* __restrict__ rowptr,
                                                  int* __restrict__ cursor) {
  int b = blockIdx.x, t = threadIdx.x;
  __shared__ int s[N_];
  int own = cnt[b * N_ + t];
  s[t] = own;
  __syncthreads();
  for (int off = 1; off < N_; off <<= 1) {
    int v = (t >= off) ? s[t - off] : 0;
    __syncthreads();
    s[t] += v;
    __syncthreads();
  }
  int excl = s[t] - own;
  rowptr[b * (N_ + 1) + t] = excl;
  cursor[b * N_ + t] = excl;
  if (t == 0) rowptr[b * (N_ + 1) + N_] = E_;
}
__global__ __launch_bounds__(256) void k_csr_fill(
    const int* __restrict__ esrc, const int* __restrict__ edst,
    const int* __restrict__ erel, int* __restrict__ cursor,
    int* __restrict__ elist) {
  int e = blockIdx.x * 256 + threadIdx.x, b = blockIdx.y;
  size_t ei = (size_t)b * E_ + e;
  int pos = atomicAdd(&cursor[b * N_ + edst[ei]], 1);
  elist[b * E_ + pos] = esrc[ei] | (erel[ei] << 9);
}

// ---------------------------------------------------------------- generic bf16 MFMA GEMM (m97-style)
// C = A[M x K](lda) @ B[N x K](ldb)^T ; 128x128 tile, BK=32, group-M swizzle.
// blockIdx.z: K-split slice (offset zA elements into A & B k-dim; C offset zC floats).
// EPI: 0 = bf16 plain, 1 = f32 plain, 2 = bf16 relu(acc+preA[hp]+preB[tp]) (bias pre-folded),
//      4 = f32 acc + (col<NH ? bias[col] : 0)   [preAB writer]
template <int KD, int EPI>
__global__ __launch_bounds__(256) void k_gemm_bt(
    const u16* __restrict__ A, int lda, const u16* __restrict__ Bm, int ldb,
    const float* __restrict__ bias, const float* __restrict__ preA,
    const float* __restrict__ preB, const int* __restrict__ pairs,
    void* __restrict__ Cv, int ldc, int ldpre, long long zA, long long zC) {
  __shared__ u16 As[128 * 32];
  __shared__ u16 Bs[128 * 32];
  int tid = threadIdx.x;
  int w = tid >> 6, lane = tid & 63;
  int wr = w >> 1, wc = w & 1;
  int lane16 = lane & 15, quad = lane >> 4;

  // group-M swizzle for L2 locality
  int nbn = gridDim.x, nbm = gridDim.y;
  int pid = blockIdx.y * nbn + blockIdx.x;
  const int GROUP = 8;
  int npg = GROUP * nbn;
  int gidg = pid / npg;
  int first = gidg * GROUP;
  int szm = min(nbm - first, GROUP);
  int pid_m = first + (pid % npg) % szm;
  int pid_n = (pid % npg) / szm;
  int n0 = pid_n * 128;
  int m0 = pid_m * 128;

  int lrow = lane >> 2;              // 0..15
  int lcol = (lane & 3) * 8;         // ushort offset within 32-col row

  f32x4 acc[4][4] = {};

  const u16* gA = A + (size_t)blockIdx.z * zA + (size_t)m0 * lda;
  const u16* gB = Bm + (size_t)blockIdx.z * zA + (size_t)n0 * ldb;

  for (int kt = 0; kt < KD; kt += 32) {
    __syncthreads();
#pragma unroll
    for (int j = 0; j < 2; j++) {
      int chunk = j * 4 + w;
      int row = chunk * 16 + lrow;
      __builtin_amdgcn_global_load_lds(
          (const AS1 void*)(gA + (size_t)row * lda + kt + lcol),
          (AS3 void*)(As + chunk * 512 + lane * 8), 16, 0, 0);
      __builtin_amdgcn_global_load_lds(
          (const AS1 void*)(gB + (size_t)row * ldb + kt + lcol),
          (AS3 void*)(Bs + chunk * 512 + lane * 8), 16, 0, 0);
    }
    __syncthreads();

    short8 af[4], bf[4];
#pragma unroll
    for (int mi = 0; mi < 4; mi++) {
      int ml = wr * 64 + mi * 16 + lane16;
      af[mi] = *(const short8*)(As + ml * 32 + quad * 8);
    }
#pragma unroll
    for (int ni = 0; ni < 4; ni++) {
      int nl = wc * 64 + ni * 16 + lane16;
      bf[ni] = *(const short8*)(Bs + nl * 32 + quad * 8);
    }
#pragma unroll
    for (int mi = 0; mi < 4; mi++)
#pragma unroll
      for (int ni = 0; ni < 4; ni++)
        acc[mi][ni] = __builtin_amdgcn_mfma_f32_16x16x32_bf16(
            af[mi], bf[ni], acc[mi][ni], 0, 0, 0);
  }

  // epilogue: D layout col=lane&15, row=quad*4+reg
  int cols[4];
  float bv[4];
#pragma unroll
  for (int ni = 0; ni < 4; ni++) {
    cols[ni] = n0 + wc * 64 + ni * 16 + lane16;
    if (EPI == 4) bv[ni] = (cols[ni] < NH) ? bias[cols[ni]] : 0.f;
  }
  float* Cf = (float*)Cv + (size_t)blockIdx.z * zC;
#pragma unroll
  for (int mi = 0; mi < 4; mi++) {
#pragma unroll
    for (int r = 0; r < 4; r++) {
      int row = m0 + wr * 64 + mi * 16 + quad * 4 + r;
      const float* pAr = nullptr;
      const float* pBr = nullptr;
      if (EPI == 2) {
        int hp = pairs[2 * row], tp = pairs[2 * row + 1];
        int pb = (row >> 10) * NE_;
        pAr = preA + (size_t)(pb + hp) * ldpre;
        pBr = preB + (size_t)(pb + tp) * ldpre;
      }
#pragma unroll
      for (int ni = 0; ni < 4; ni++) {
        float v = acc[mi][ni][r];
        int col = cols[ni];
        if (EPI == 0) {
          ((u16*)Cv)[(size_t)row * ldc + col] = f2bf(v);
        } else if (EPI == 1) {
          Cf[(size_t)row * ldc + col] = v;
        } else if (EPI == 2) {
          v += pAr[col] + pBr[col];
          ((u16*)Cv)[(size_t)row * ldc + col] = f2bf(fmaxf(v, 0.f));
        } else if (EPI == 4) {
          Cf[(size_t)row * ldc + col] = v + bv[ni];
        }
      }
    }
  }
}

// ---------------------------------------------------------------- mlp2 partial reduce: out = sum_z part[z] + b2
__global__ __launch_bounds__(128) void k_out_reduce(
    const float* __restrict__ part, const float* __restrict__ b2,
    float* __restrict__ out) {
  int row = blockIdx.x, c = threadIdx.x;
  if (c >= OUT_) return;
  float s = b2[c];
#pragma unroll
  for (int z = 0; z < NZ; z++)
    s += part[(size_t)z * (B_ * P_ * 128) + (size_t)row * 128 + c];
  out[(size_t)row * OUT_ + c] = s;
}

// ---------------------------------------------------------------- edge aggregation (CSR)
__global__ __launch_bounds__(256) void k_agg(
    const u16* __restrict__ Hr, const int* __restrict__ rowptr,
    const int* __restrict__ elist, const float* __restrict__ gnn_b, int layer,
    float* __restrict__ hout, u16* __restrict__ houtB) {
  int n = blockIdx.x, b = blockIdx.y;
  int beg = rowptr[b * (N_ + 1) + n], end = rowptr[b * (N_ + 1) + n + 1];
  const int* el = elist + (size_t)b * E_;
  const u16* HrB = Hr + (size_t)b * N_ * NW;
  int tid = threadIdx.x;
  for (int c = tid; c < D_; c += 256) {
    float acc = bf2f(HrB[(size_t)n * NW + R_ * D_ + c]) + gnn_b[layer * D_ + c];
    for (int i = beg; i < end; i++) {
      int pk = el[i];
      acc += bf2f(HrB[(size_t)(pk & 511) * NW + (pk >> 9) * D_ + c]);
    }
    float r = fmaxf(acc, 0.f);
    hout[((size_t)b * N_ + n) * D_ + c] = r;
    houtB[((size_t)b * N_ + n) * D_ + c] = f2bf(r);
  }
}

// ---------------------------------------------------------------- entity mention-mean (f32 + bf16 out)
__global__ __launch_bounds__(256) void k_ent(
    const float* __restrict__ h0, const float* __restrict__ h1,
    const int* __restrict__ e2m, const float* __restrict__ e2m_mask,
    float* __restrict__ ent, u16* __restrict__ entB) {
  int e = blockIdx.x, b = blockIdx.y;
  __shared__ int idx_s[MM_];
  __shared__ float msk_s[MM_];
  int tid = threadIdx.x;
  if (tid < MM_) {
    idx_s[tid] = e2m[((size_t)b * NE_ + e) * MM_ + tid];
    msk_s[tid] = e2m_mask[((size_t)b * NE_ + e) * MM_ + tid];
  }
  __syncthreads();
  float msum = 0.f;
#pragma unroll
  for (int m = 0; m < MM_; m++) msum += msk_s[m];
  float inv = 1.f / (msum + 1e-7f);
  for (int c = tid; c < EE2; c += 256) {
    const float* base = (c < D_) ? h0 : h1;
    int cc = (c < D_) ? c : c - D_;
    float s = 0.f;
#pragma unroll
    for (int m = 0; m < MM_; m++) {
      int j = idx_s[m];
      if (j > 0) s += base[((size_t)b * N_ + (j - 1)) * D_ + cc] * msk_s[m];
    }
    float v = s * inv;
    ent[((size_t)b * NE_ + e) * EE2 + c] = v;
    entB[((size_t)b * NE_ + e) * EE2 + c] = f2bf(v);
  }
}

// ---------------------------------------------------------------- featC: [|hf-tf|, hf*tf] bf16 (4096 x 3200)
__global__ __launch_bounds__(256) void k_featC(
    const float* __restrict__ ent, const int* __restrict__ ent_pair,
    u16* __restrict__ featC) {
  int row = blockIdx.x;                 // 0..4095
  int b = row >> 10, g = row & 1023;
  int hp = ent_pair[(((size_t)b << 10) + g) * 2 + 0];
  int tp = ent_pair[(((size_t)b << 10) + g) * 2 + 1];
  const float* eh = ent + ((size_t)b * NE_ + hp) * EE2;
  const float* et = ent + ((size_t)b * NE_ + tp) * EE2;
  u16* orow = featC + (size_t)row * NH;
  for (int c = threadIdx.x; c < 800; c += 256) {   // float4 chunks, 2 segs
    int seg = c / 400, kk = (c - seg * 400) * 4;
    float4 hf = *(const float4*)(eh + kk);
    float4 tf = *(const float4*)(et + kk);
    float4 v;
    if (seg == 0) {
      v.x = fabsf(hf.x - tf.x); v.y = fabsf(hf.y - tf.y);
      v.z = fabsf(hf.z - tf.z); v.w = fabsf(hf.w - tf.w);
    } else {
      v.x = hf.x * tf.x; v.y = hf.y * tf.y;
      v.z = hf.z * tf.z; v.w = hf.w * tf.w;
    }
    ushort4 o;
    o.x = f2bf(v.x); o.y = f2bf(v.y); o.z = f2bf(v.z); o.w = f2bf(v.w);
    *(ushort4*)(orow + seg * EE2 + kk) = o;
  }
}

// ----------------------------------------------------------------
extern "C" void kernel_launch(void* const* d_in, const int* in_sizes, int n_in,
                              void* d_out, int out_size, void* d_ws, size_t ws_size,
                              hipStream_t stream) {
  const float* token_feature = (const float*)d_in[0];
  const float* doc_cls       = (const float*)d_in[1];
  const int*   span_pos      = (const int*)d_in[2];
  const float* span_mask     = (const float*)d_in[3];
  const int*   node_ner      = (const int*)d_in[4];
  const float* node_mask     = (const float*)d_in[5];
  const int*   e2m           = (const int*)d_in[6];
  const float* e2m_mask      = (const float*)d_in[7];
  const int*   ent_pair      = (const int*)d_in[8];
  const int*   edge_src      = (const int*)d_in[9];
  const int*   edge_dst      = (const int*)d_in[10];
  const int*   edge_rel      = (const int*)d_in[11];
  const int*   ment_num      = (const int*)d_in[12];
  const float* nerEmb        = (const float*)d_in[13];
  const float* doc_W         = (const float*)d_in[14];
  const float* doc_b         = (const float*)d_in[15];
  const float* W_rel         = (const float*)d_in[16];
  const float* W_self        = (const float*)d_in[17];
  const float* gnn_b         = (const float*)d_in[18];
  const float* W1            = (const float*)d_in[19];
  const float* b1            = (const float*)d_in[20];
  const float* W2            = (const float*)d_in[21];
  const float* b2            = (const float*)d_in[22];
  float* out = (float*)d_out;

  float* ws = (float*)d_ws;
  size_t off = 0;
  auto alloc = [&](size_t n) {
    float* p = ws + off;
    off += (n + 63) & ~size_t(63);
    return p;
  };
  float* doc_proj = alloc(B_ * D_);
  u16*   xB  = (u16*)alloc((size_t)B_ * N_ * D_ / 2);
  float* h0  = alloc((size_t)B_ * N_ * D_);
  float* h1  = alloc((size_t)B_ * N_ * D_);
  u16*   hB  = (u16*)alloc((size_t)B_ * N_ * D_ / 2);
  float* ent = alloc((size_t)B_ * NE_ * EE2);
  u16*   entB = (u16*)alloc((size_t)B_ * NE_ * EE2 / 2);
  u16*   WT    = (u16*)alloc((size_t)L_ * NW * D_ / 2);
  u16*   W1abT = (u16*)alloc((size_t)KF * EE2 / 2);      // 6400 x 1600
  u16*   W1cdT = (u16*)alloc((size_t)NH * NH / 2);       // 3200 x 3200
  u16*   W2T   = (u16*)alloc((size_t)128 * NH / 2);
  float* preAB = alloc((size_t)B_ * NE_ * KF);           // 256 x 6400
  // Hr (1024x12800 u16) and featC (4096x3200 u16) same size; Hr dead after agg
  u16*   Hr    = (u16*)alloc((size_t)B_ * N_ * NW / 2);
  u16*   featC = Hr;
  u16*   hiddenB = (u16*)alloc((size_t)B_ * P_ * NH / 2);
  float* part    = alloc((size_t)NZ * B_ * P_ * 128);    // mlp2 partials
  int*   csr_cnt    = (int*)alloc(B_ * N_ / 1 * sizeof(int) / 4);
  int*   csr_rowptr = (int*)alloc(B_ * (N_ + 1));
  int*   csr_cursor = (int*)alloc(B_ * N_);
  int*   csr_elist  = (int*)alloc(B_ * E_);
  (void)ws_size;

  // CSR build (independent of everything; used by both agg layers)
  k_csr_zero<<<dim3(B_), 256, 0, stream>>>(csr_cnt);
  k_csr_count<<<dim3(E_ / 256, B_), 256, 0, stream>>>(edge_dst, csr_cnt);
  k_csr_scan<<<dim3(B_), 256, 0, stream>>>(csr_cnt, csr_rowptr, csr_cursor);
  k_csr_fill<<<dim3(E_ / 256, B_), 256, 0, stream>>>(edge_src, edge_dst, edge_rel,
                                                     csr_cursor, csr_elist);

  // weight prep (independent of data path)
  k_wt<<<dim3(D_ / 32, D_ / 32, L_ * 16), 256, 0, stream>>>(W_rel, W_self, WT);
  k_w1t<<<dim3(KF / 32, NH / 32), 256, 0, stream>>>(W1, W1abT, W1cdT);
  k_w2t<<<dim3(NH / 32, 4), 256, 0, stream>>>(W2, W2T);

  k_doc_proj<<<dim3((B_ * D_ + 255) / 256), 256, 0, stream>>>(doc_cls, doc_W, doc_b, doc_proj);
  k_build_node<<<dim3(N_, B_), 256, 0, stream>>>(token_feature, doc_cls, span_pos, span_mask,
                                                 node_ner, node_mask, ment_num, nerEmb,
                                                 doc_proj, xB);
  // GNN layers
  const u16* hin = xB;
  float* houts[2] = {h0, h1};
  for (int l = 0; l < L_; l++) {
    k_gemm_bt<D_, 0><<<dim3(NW / 128, (B_ * N_) / 128), 256, 0, stream>>>(
        hin, D_, WT + (size_t)l * NW * D_, D_, nullptr, nullptr, nullptr, nullptr,
        Hr, NW, 0, 0, 0);
    k_agg<<<dim3(N_, B_), 256, 0, stream>>>(Hr, csr_rowptr, csr_elist,
                                            gnn_b, l, houts[l], hB);
    hin = hB;
  }
  k_ent<<<dim3(NE_, B_), 256, 0, stream>>>(h0, h1, e2m, e2m_mask, ent, entB);

  // preAB = ent @ [W1a | W1b] (+b1 on a-half)   M=256, K=1600, N=6400
  k_gemm_bt<EE2, 4><<<dim3(KF / 128, (B_ * NE_) / 128), 256, 0, stream>>>(
      entB, EE2, W1abT, EE2, b1, nullptr, nullptr, nullptr, preAB, KF, 0, 0, 0);

  k_featC<<<dim3(B_ * P_), 256, 0, stream>>>(ent, ent_pair, featC);

  // big GEMM: hidden = relu(featC @ W1cd^T + preAB[hp][c] + preAB[tp][3200+c])
  k_gemm_bt<NH, 2><<<dim3(NH / 128, (B_ * P_) / 128), 256, 0, stream>>>(
      featC, NH, W1cdT, NH, nullptr, preAB, preAB + NH, ent_pair, hiddenB, NH,
      KF, 0, 0);

  // mlp2 split-K partials: part[z] = hiddenB[:, z*800:(z+1)*800] @ W2T_k-slice^T
  k_gemm_bt<KS, 1><<<dim3(1, (B_ * P_) / 128, NZ), 256, 0, stream>>>(
      hiddenB, NH, W2T, NH, nullptr, nullptr, nullptr, nullptr, part, 128,
      0, KS, (long long)B_ * P_ * 128);
  k_out_reduce<<<dim3(B_ * P_), 128, 0, stream>>>(part, b2, out);
}